// Round 9
// baseline (1940.666 us; speedup 1.0000x reference)
//
#include <hip/hip_runtime.h>
#include <hip/hip_bf16.h>
#include <math.h>

// BernNet: h = relu(x@W1+b1)@W2+b2 ; out = sum_m c_m A^m h (Horner) ; log_softmax
// A = D^-1/2 Adj D^-1/2. CSR(dst) via bucketed counting sort (no per-edge global
// atomics). Horner SpMV: feature dim split into 4 quarter-planes [4][N][16] bf16
// (3.2MB each, fits per-XCD 4MB L2); one kernel/step sweeps quarters sequentially.
// NOTE: nontemporal loads on csr REGRESSED ~+195us (bypassed L2/L3; round 6).

#define NFEAT 512
#define HIDDEN 128
#define NCLASS 64
#define KORD 10
#define MAXBUCK 1600   // LDS histogram capacity (N <= 102400)
#define CH 8192        // edges per block in bucket passes (391 blocks)

typedef unsigned short ushort_t;
typedef __attribute__((ext_vector_type(8))) short short8;
typedef __attribute__((ext_vector_type(4))) float f32x4;
typedef __attribute__((ext_vector_type(8))) unsigned short us8v;

static __device__ __forceinline__ float bf2f(ushort_t u) {
    return __uint_as_float(((unsigned)u) << 16);
}
static __device__ __forceinline__ ushort_t f2bf(float f) {
    __hip_bfloat16 h = __float2bfloat16(f);
    return *reinterpret_cast<ushort_t*>(&h);
}
static __device__ __forceinline__ short8 pack8(float4 a, float4 b) {
    short8 r;
    r[0] = (short)f2bf(a.x); r[1] = (short)f2bf(a.y);
    r[2] = (short)f2bf(a.z); r[3] = (short)f2bf(a.w);
    r[4] = (short)f2bf(b.x); r[5] = (short)f2bf(b.y);
    r[6] = (short)f2bf(b.z); r[7] = (short)f2bf(b.w);
    return r;
}

// ---------------- graph build: bucketed counting sort ----------------

__global__ __launch_bounds__(256) void p0_hist(const int* __restrict__ src,
                                               const int* __restrict__ dst,
                                               int* __restrict__ bhist,  // [2*MAXBUCK]
                                               int E, int nbuck) {
    __shared__ int hd[MAXBUCK];
    __shared__ int hs[MAXBUCK];
    for (int i = threadIdx.x; i < nbuck; i += 256) { hd[i] = 0; hs[i] = 0; }
    __syncthreads();
    int base = blockIdx.x * CH;
    int lim = min(base + CH, E);
    for (int e = base + threadIdx.x; e < lim; e += 256) {
        atomicAdd(&hd[dst[e] >> 6], 1);
        atomicAdd(&hs[src[e] >> 6], 1);
    }
    __syncthreads();
    for (int i = threadIdx.x; i < nbuck; i += 256) {
        int v = hd[i];
        if (v) atomicAdd(&bhist[i], v);
        int w = hs[i];
        if (w) atomicAdd(&bhist[MAXBUCK + i], w);
    }
}

__global__ __launch_bounds__(256) void p_scan(const int* __restrict__ bhist,
                                              int* __restrict__ bstart,
                                              int* __restrict__ gpos,
                                              int* __restrict__ sstart,
                                              int* __restrict__ spos, int nbuck,
                                              int* __restrict__ row_ptr, int N, int E) {
    __shared__ int ws[4];
    __shared__ int carry;
    int t = threadIdx.x, lane = t & 63, w = t >> 6;
    #pragma unroll
    for (int pass = 0; pass < 2; ++pass) {
        const int* in = bhist + pass * MAXBUCK;
        int* o1 = pass ? sstart : bstart;
        int* o2 = pass ? spos : gpos;
        if (t == 0) carry = 0;
        __syncthreads();
        for (int base = 0; base < nbuck; base += 256) {
            int i = base + t;
            int v = (i < nbuck) ? in[i] : 0;
            int s = v;
            #pragma unroll
            for (int off = 1; off < 64; off <<= 1) {
                int u = __shfl_up(s, off);
                if (lane >= off) s += u;
            }
            if (lane == 63) ws[w] = s;
            __syncthreads();
            int pre = 0;
            #pragma unroll
            for (int j = 0; j < 4; ++j)
                if (j < w) pre += ws[j];
            int excl = carry + pre + s - v;
            if (i < nbuck) {
                o1[i] = excl;
                o2[i] = excl;
            }
            __syncthreads();
            if (t == 255) carry += pre + s;
            __syncthreads();
        }
        if (t == 0) o1[nbuck] = E;
        __syncthreads();
    }
    if (t == 0) row_ptr[N] = E;
}

__global__ __launch_bounds__(256) void p1_scatter(const int* __restrict__ src,
                                                  const int* __restrict__ dst,
                                                  int* __restrict__ gpos,
                                                  int* __restrict__ spos,
                                                  int* __restrict__ buf,
                                                  unsigned char* __restrict__ sbuf,
                                                  int E, int nbuck) {
    __shared__ int hd[MAXBUCK];
    __shared__ int bd[MAXBUCK];
    __shared__ int hs[MAXBUCK];
    __shared__ int bs[MAXBUCK];
    for (int i = threadIdx.x; i < nbuck; i += 256) { hd[i] = 0; hs[i] = 0; }
    __syncthreads();
    int base = blockIdx.x * CH;
    int lim = min(base + CH, E);
    for (int e = base + threadIdx.x; e < lim; e += 256) {
        atomicAdd(&hd[dst[e] >> 6], 1);
        atomicAdd(&hs[src[e] >> 6], 1);
    }
    __syncthreads();
    for (int i = threadIdx.x; i < nbuck; i += 256) {
        int v = hd[i];
        bd[i] = v ? atomicAdd(&gpos[i], v) : 0;
        hd[i] = 0;
        int u = hs[i];
        bs[i] = u ? atomicAdd(&spos[i], u) : 0;
        hs[i] = 0;
    }
    __syncthreads();
    for (int e = base + threadIdx.x; e < lim; e += 256) {
        int d = dst[e], s = src[e];
        int bk = d >> 6;
        int off = atomicAdd(&hd[bk], 1);
        buf[bd[bk] + off] = s | ((d & 63) << 17);
        int sk = s >> 6;
        int off2 = atomicAdd(&hs[sk], 1);
        sbuf[bs[sk] + off2] = (unsigned char)(s & 63);
    }
}

__global__ __launch_bounds__(256) void p2_group(const int* __restrict__ buf,
                                                const int* __restrict__ bstart,
                                                int* __restrict__ csr,
                                                int* __restrict__ row_ptr, int N) {
    int bk = blockIdx.x;
    int s0 = bstart[bk], s1 = bstart[bk + 1];
    __shared__ int cnt[64];
    __shared__ int pos[64];
    int t = threadIdx.x;
    if (t < 64) cnt[t] = 0;
    __syncthreads();
    for (int i = s0 + t; i < s1; i += 256) atomicAdd(&cnt[buf[i] >> 17], 1);
    __syncthreads();
    if (t < 64) {
        int v = cnt[t], s = v;
        #pragma unroll
        for (int off = 1; off < 64; off <<= 1) {
            int u = __shfl_up(s, off);
            if (t >= off) s += u;
        }
        int excl = s - v;
        int node = bk * 64 + t;
        if (node < N) row_ptr[node] = s0 + excl;
        pos[t] = s0 + excl;
    }
    __syncthreads();
    for (int i = s0 + t; i < s1; i += 256) {
        int p = buf[i];
        int off = atomicAdd(&pos[p >> 17], 1);
        csr[off] = p & 0x1FFFF;
    }
}

__global__ __launch_bounds__(256) void p2b_deg(const unsigned char* __restrict__ sbuf,
                                               const int* __restrict__ sstart,
                                               float* __restrict__ dinv, int N) {
    int bk = blockIdx.x;
    int s0 = sstart[bk], s1 = sstart[bk + 1];
    __shared__ int cnt[64];
    int t = threadIdx.x;
    if (t < 64) cnt[t] = 0;
    __syncthreads();
    for (int i = s0 + t; i < s1; i += 256) atomicAdd(&cnt[sbuf[i]], 1);
    __syncthreads();
    if (t < 64) {
        int node = bk * 64 + t;
        if (node < N) {
            int d = cnt[t];
            dinv[node] = (d > 0) ? rsqrtf((float)d) : 0.0f;
        }
    }
}

// ---------------- Bernstein coefficients ----------------

__global__ void k_coef(const float* __restrict__ temp, float* __restrict__ c,
                       float* __restrict__ temp_out) {
    if (threadIdx.x != 0 || blockIdx.x != 0) return;
    float T[KORD + 1];
    #pragma unroll
    for (int j = 0; j <= KORD; ++j) {
        T[j] = fmaxf(temp[j], 0.0f);
        temp_out[j] = T[j];
    }
    float binom[KORD + 1][KORD + 1];
    for (int n = 0; n <= KORD; ++n) {
        binom[n][0] = 1.0f;
        for (int k = 1; k <= n; ++k)
            binom[n][k] = (k == n) ? 1.0f : binom[n - 1][k - 1] + binom[n - 1][k];
        for (int k = n + 1; k <= KORD; ++k) binom[n][k] = 0.0f;
    }
    for (int m = 0; m <= KORD; ++m) {
        float s = 0.0f;
        for (int j = 0; j <= KORD; ++j) {
            float cj = 0.0f;
            for (int p = 0; p <= j && p <= m; ++p) {
                int q = m - p;
                if (q > KORD - j) continue;
                float t = binom[j][p] * binom[KORD - j][q];
                cj += (p & 1) ? -t : t;
            }
            s += binom[KORD][j] * T[j] * cj;
        }
        c[m] = s * (1.0f / 1024.0f);
    }
}

// ---------------- weight prep: transpose + bf16 ----------------

__global__ void k_prepw(const float* __restrict__ W1, const float* __restrict__ W2,
                        ushort_t* __restrict__ W1t, ushort_t* __restrict__ W2t) {
    int id = blockIdx.x * blockDim.x + threadIdx.x;
    if (id < HIDDEN * NFEAT) {
        int n = id / NFEAT, k = id % NFEAT;
        W1t[id] = f2bf(W1[(size_t)k * HIDDEN + n]);
    } else if (id < HIDDEN * NFEAT + NCLASS * HIDDEN) {
        int j = id - HIDDEN * NFEAT;
        int n = j / HIDDEN, k = j % HIDDEN;
        W2t[j] = f2bf(W2[(size_t)k * NCLASS + n]);
    }
}

// ---------------- GEMM1: h1 = relu(x @ W1 + b1), bf16 MFMA ----------------

__global__ __launch_bounds__(256) void gemm1(const float* __restrict__ x,
                                             const ushort_t* __restrict__ W1t,
                                             const float* __restrict__ b1,
                                             ushort_t* __restrict__ h1, int M) {
    __shared__ char smem[24576];
    char* As = smem;
    char* Bs = smem + 8192;
    const int t = threadIdx.x;
    const int m0 = blockIdx.x * 64;
    const int wid = t >> 6, lane = t & 63;
    const int wr = wid >> 1, wc = wid & 1;
    const int lm = lane & 15, lg = lane >> 4;

    f32x4 acc[2][4];
    #pragma unroll
    for (int i = 0; i < 2; ++i)
        #pragma unroll
        for (int j = 0; j < 4; ++j) acc[i][j] = (f32x4){0.f, 0.f, 0.f, 0.f};

    for (int k0 = 0; k0 < NFEAT; k0 += 64) {
        #pragma unroll
        for (int i = 0; i < 2; ++i) {
            int idx = t + i * 256;
            int r = idx >> 3, c8 = idx & 7;
            float4 v0 = make_float4(0.f, 0.f, 0.f, 0.f), v1 = v0;
            if (m0 + r < M) {
                const float* p = &x[(size_t)(m0 + r) * NFEAT + k0 + c8 * 8];
                v0 = *(const float4*)p;
                v1 = *(const float4*)(p + 4);
            }
            *(short8*)(As + r * 128 + ((c8 * 16) ^ ((r & 7) << 4))) = pack8(v0, v1);
        }
        #pragma unroll
        for (int i = 0; i < 4; ++i) {
            int idx = t + i * 256;
            int r = idx >> 3, c8 = idx & 7;
            short8 v = *(const short8*)&W1t[(size_t)r * NFEAT + k0 + c8 * 8];
            *(short8*)(Bs + r * 128 + ((c8 * 16) ^ ((r & 7) << 4))) = v;
        }
        __syncthreads();
        #pragma unroll
        for (int kk = 0; kk < 64; kk += 32) {
            int kb = (kk + lg * 8) * 2;
            short8 af[2], bfr[4];
            #pragma unroll
            for (int fi = 0; fi < 2; ++fi) {
                int m = wr * 32 + fi * 16 + lm;
                af[fi] = *(const short8*)(As + m * 128 + (kb ^ ((m & 7) << 4)));
            }
            #pragma unroll
            for (int fj = 0; fj < 4; ++fj) {
                int n = wc * 64 + fj * 16 + lm;
                bfr[fj] = *(const short8*)(Bs + n * 128 + (kb ^ ((n & 7) << 4)));
            }
            #pragma unroll
            for (int fi = 0; fi < 2; ++fi)
                #pragma unroll
                for (int fj = 0; fj < 4; ++fj)
                    acc[fi][fj] = __builtin_amdgcn_mfma_f32_16x16x32_bf16(
                        af[fi], bfr[fj], acc[fi][fj], 0, 0, 0);
        }
        __syncthreads();
    }

    ushort_t* Cs = (ushort_t*)smem;
    #pragma unroll
    for (int fi = 0; fi < 2; ++fi)
        #pragma unroll
        for (int fj = 0; fj < 4; ++fj) {
            int col = wc * 64 + fj * 16 + lm;
            float bb = b1[col];
            #pragma unroll
            for (int q = 0; q < 4; ++q) {
                int r = wr * 32 + fi * 16 + lg * 4 + q;
                float z = fmaxf(acc[fi][fj][q] + bb, 0.0f);
                Cs[r * 128 + col] = f2bf(z);
            }
        }
    __syncthreads();
    #pragma unroll
    for (int i = 0; i < 4; ++i) {
        int idx = t + i * 256;
        int r = idx >> 4, c8 = idx & 15;
        if (m0 + r < M)
            *(short8*)&h1[(size_t)(m0 + r) * HIDDEN + c8 * 8] =
                *(const short8*)&Cs[r * 128 + c8 * 8];
    }
}

// ---------------- GEMM2: h = h1 @ W2 + b2 ; emits hb, g0 in quarter-plane layout --
// plane q holds features [q*16, q*16+16): hb[q*N*16 + node*16 + f]

__global__ __launch_bounds__(256) void gemm2(const ushort_t* __restrict__ h1,
                                             const ushort_t* __restrict__ W2t,
                                             const float* __restrict__ b2,
                                             const float* __restrict__ dinv,
                                             const float* __restrict__ c,
                                             ushort_t* __restrict__ hb,
                                             ushort_t* __restrict__ g0, int M, int N) {
    __shared__ char smem[49152];
    char* As = smem;
    char* Bs = smem + 32768;
    const int t = threadIdx.x;
    const int m0 = blockIdx.x * 128;
    const int wr = t >> 6, lane = t & 63;
    const int lm = lane & 15, lg = lane >> 4;

    #pragma unroll
    for (int i = 0; i < 8; ++i) {
        int idx = t + i * 256;
        int r = idx >> 4, c8 = idx & 15;
        short8 v = (short8){0, 0, 0, 0, 0, 0, 0, 0};
        if (m0 + r < M) v = *(const short8*)&h1[(size_t)(m0 + r) * HIDDEN + c8 * 8];
        *(short8*)(As + r * 256 + ((c8 * 16) ^ ((r & 7) << 4))) = v;
    }
    #pragma unroll
    for (int i = 0; i < 4; ++i) {
        int idx = t + i * 256;
        int r = idx >> 4, c8 = idx & 15;
        short8 v = *(const short8*)&W2t[(size_t)r * HIDDEN + c8 * 8];
        *(short8*)(Bs + r * 256 + ((c8 * 16) ^ ((r & 7) << 4))) = v;
    }
    __syncthreads();

    f32x4 acc[2][4];
    #pragma unroll
    for (int i = 0; i < 2; ++i)
        #pragma unroll
        for (int j = 0; j < 4; ++j) acc[i][j] = (f32x4){0.f, 0.f, 0.f, 0.f};

    #pragma unroll
    for (int kk = 0; kk < HIDDEN; kk += 32) {
        int kb = (kk + lg * 8) * 2;
        short8 af[2], bfr[4];
        #pragma unroll
        for (int fi = 0; fi < 2; ++fi) {
            int m = wr * 32 + fi * 16 + lm;
            af[fi] = *(const short8*)(As + m * 256 + (kb ^ ((m & 7) << 4)));
        }
        #pragma unroll
        for (int fj = 0; fj < 4; ++fj) {
            int n = fj * 16 + lm;
            bfr[fj] = *(const short8*)(Bs + n * 256 + (kb ^ ((n & 7) << 4)));
        }
        #pragma unroll
        for (int fi = 0; fi < 2; ++fi)
            #pragma unroll
            for (int fj = 0; fj < 4; ++fj)
                acc[fi][fj] = __builtin_amdgcn_mfma_f32_16x16x32_bf16(
                    af[fi], bfr[fj], acc[fi][fj], 0, 0, 0);
    }

    float cK = c[KORD];
    #pragma unroll
    for (int fi = 0; fi < 2; ++fi)
        #pragma unroll
        for (int q = 0; q < 4; ++q) {
            int r = m0 + wr * 32 + fi * 16 + lg * 4 + q;
            if (r < M) {
                float dv = dinv[r];
                #pragma unroll
                for (int fj = 0; fj < 4; ++fj) {
                    int col = fj * 16 + lm;
                    float z = acc[fi][fj][q] + b2[col];
                    size_t o = (size_t)fj * N * 16 + (size_t)r * 16 + lm;
                    hb[o] = f2bf(z);
                    g0[o] = f2bf(dv * cK * z);
                }
            }
        }
}

// ---------------- Horner SpMV step (quarter-plane): w_q = A*g_q + c*h_q ----------
// grid = 4*nblk: quarter q = blockIdx.x/nblk (sweeps sequentially -> plane q is
// L2-resident, 3.2MB < 4MB/XCD). 2 lanes/edge, ushort8 (8 feats,16B)/lane,
// 32 edges per wave-load.

__global__ __launch_bounds__(256) void k_adj_q(const ushort_t* __restrict__ gin,
                                               const ushort_t* __restrict__ hb,
                                               const float* __restrict__ dinv,
                                               const int* __restrict__ row_ptr,
                                               const int* __restrict__ csr,
                                               const float* __restrict__ c, int cidx,
                                               ushort_t* __restrict__ gout,
                                               float* __restrict__ out, int last,
                                               int N, int nblk) {
    int q = blockIdx.x / nblk;
    int nb = blockIdx.x - q * nblk;
    int wid = nb * 4 + (threadIdx.x >> 6);
    int lane = threadIdx.x & 63;
    if (wid >= N) return;
    const int g = lane >> 1;         // edge slot (0..31)
    const int fh = lane & 1;         // feature 8-half within quarter
    const ushort_t* ginq = gin + (size_t)q * N * 16;
    int b = row_ptr[wid], e = row_ptr[wid + 1];

    float a[8] = {0.f, 0.f, 0.f, 0.f, 0.f, 0.f, 0.f, 0.f};
    for (int i = b; i < e; i += 32) {
        int ei = i + g;
        bool ok = ei < e;
        int s = ok ? csr[ei] : 0;
        us8v v = *(const us8v*)&ginq[(size_t)s * 16 + fh * 8];
        float m = ok ? 1.0f : 0.0f;
        #pragma unroll
        for (int p = 0; p < 8; ++p) a[p] += m * bf2f(v[p]);
    }
    // combine the 32 edge-groups (lanes with equal fh)
    #pragma unroll
    for (int off = 2; off <= 32; off <<= 1)
        #pragma unroll
        for (int p = 0; p < 8; ++p) a[p] += __shfl_xor(a[p], off);

    float dv = dinv[wid];
    float cc = c[cidx];
    size_t o = (size_t)q * N * 16 + (size_t)wid * 16 + fh * 8;
    us8v hv = *(const us8v*)&hb[o];
    float w[8];
    #pragma unroll
    for (int p = 0; p < 8; ++p) w[p] = dv * a[p] + cc * bf2f(hv[p]);

    if (g == 0) {
        if (!last) {
            us8v r;
            #pragma unroll
            for (int p = 0; p < 8; ++p) r[p] = f2bf(dv * w[p]);
            *(us8v*)&gout[o] = r;
        } else {
            size_t oo = (size_t)wid * NCLASS + q * 16 + fh * 8;
            float4 r0 = make_float4(w[0], w[1], w[2], w[3]);
            float4 r1 = make_float4(w[4], w[5], w[6], w[7]);
            *(float4*)&out[oo] = r0;
            *(float4*)&out[oo + 4] = r1;
        }
    }
}

// ---------------- log_softmax over rows of 64 (in place on out) ----------------

__global__ __launch_bounds__(256) void k_logsm(float* __restrict__ out, int N) {
    int wid = blockIdx.x * 4 + (threadIdx.x >> 6);
    int lane = threadIdx.x & 63;
    if (wid >= N) return;
    float val = out[(size_t)wid * NCLASS + lane];
    float mx = val;
    #pragma unroll
    for (int off = 32; off >= 1; off >>= 1) mx = fmaxf(mx, __shfl_xor(mx, off));
    float ex = expf(val - mx), s = ex;
    #pragma unroll
    for (int off = 32; off >= 1; off >>= 1) s += __shfl_xor(s, off);
    out[(size_t)wid * NCLASS + lane] = val - mx - logf(s);
}

// ---------------- launch ----------------

extern "C" void kernel_launch(void* const* d_in, const int* in_sizes, int n_in,
                              void* d_out, int out_size, void* d_ws, size_t ws_size,
                              hipStream_t stream) {
    const float* x = (const float*)d_in[0];
    const int* ei = (const int*)d_in[1];
    const float* W1 = (const float*)d_in[2];
    const float* b1 = (const float*)d_in[3];
    const float* W2 = (const float*)d_in[4];
    const float* b2 = (const float*)d_in[5];
    const float* temp = (const float*)d_in[6];

    const int N = in_sizes[0] / NFEAT;  // 100000
    const int E = in_sizes[1] / 2;      // 3200000
    const int* src = ei;
    const int* dst = ei + E;
    const int nbuck = (N + 63) >> 6;    // 1563

    float* out = (float*)d_out;
    float* temp_out = out + (size_t)N * NCLASS;

    char* ws = (char*)d_ws;
    size_t off = 0;
    auto alloc = [&](size_t bytes) {
        char* p = ws + off;
        off = (off + bytes + 255) & ~(size_t)255;
        return p;
    };
    ushort_t* h1 = (ushort_t*)alloc((size_t)N * HIDDEN * sizeof(ushort_t));  // 25.6MB
    ushort_t* hb = (ushort_t*)alloc((size_t)N * NCLASS * sizeof(ushort_t));  // [4][N][16]
    ushort_t* gA = (ushort_t*)alloc((size_t)N * NCLASS * sizeof(ushort_t));  // [4][N][16]
    ushort_t* gB = (ushort_t*)alloc((size_t)N * NCLASS * sizeof(ushort_t));  // [4][N][16]
    float* dinv = (float*)alloc((size_t)N * sizeof(float));
    int* row_ptr = (int*)alloc((size_t)(N + 1) * sizeof(int));
    int* bhist = (int*)alloc((size_t)(2 * MAXBUCK) * sizeof(int));
    int* bstart = (int*)alloc((size_t)(MAXBUCK + 1) * sizeof(int));
    int* gpos = (int*)alloc((size_t)MAXBUCK * sizeof(int));
    int* sstart = (int*)alloc((size_t)(MAXBUCK + 1) * sizeof(int));
    int* spos = (int*)alloc((size_t)MAXBUCK * sizeof(int));
    int* csr = (int*)alloc((size_t)E * sizeof(int));
    ushort_t* W1t = (ushort_t*)alloc((size_t)HIDDEN * NFEAT * sizeof(ushort_t));
    ushort_t* W2t = (ushort_t*)alloc((size_t)NCLASS * HIDDEN * sizeof(ushort_t));
    float* c = (float*)alloc(64);
    (void)ws_size;

    // scratch aliased onto h1 (dead until gemm1): buf 12.8MB + sbuf 3.2MB < 25.6MB
    int* buf = (int*)h1;
    unsigned char* sbuf = (unsigned char*)h1 + (size_t)13 * 1024 * 1024;

    const int TB = 256;
    const int eg = (E + CH - 1) / CH;  // 391
    const int nblk = (N + 3) / 4;      // node-blocks (4 waves each)

    hipMemsetAsync(bhist, 0, (size_t)(2 * MAXBUCK) * sizeof(int), stream);
    p0_hist<<<eg, TB, 0, stream>>>(src, dst, bhist, E, nbuck);
    p_scan<<<1, TB, 0, stream>>>(bhist, bstart, gpos, sstart, spos, nbuck, row_ptr, N, E);
    p1_scatter<<<eg, TB, 0, stream>>>(src, dst, gpos, spos, buf, sbuf, E, nbuck);
    p2_group<<<nbuck, TB, 0, stream>>>(buf, bstart, csr, row_ptr, N);
    p2b_deg<<<nbuck, TB, 0, stream>>>(sbuf, sstart, dinv, N);

    k_coef<<<1, 64, 0, stream>>>(temp, c, temp_out);
    k_prepw<<<(HIDDEN * NFEAT + NCLASS * HIDDEN + TB - 1) / TB, TB, 0, stream>>>(W1, W2, W1t, W2t);

    gemm1<<<(N + 63) / 64, TB, 0, stream>>>(x, W1t, b1, h1, N);
    gemm2<<<(N + 127) / 128, TB, 0, stream>>>(h1, W2t, b2, dinv, c, hb, gA, N, N);

    const ushort_t* gin = gA;
    ushort_t* gout = gB;
    for (int s = 1; s <= KORD; ++s) {
        int last = (s == KORD) ? 1 : 0;
        k_adj_q<<<4 * nblk, TB, 0, stream>>>(gin, hb, dinv, row_ptr, csr, c, KORD - s,
                                             gout, out, last, N, nblk);
        const ushort_t* tmp = gin;
        gin = gout;
        gout = (ushort_t*)tmp;
    }
    k_logsm<<<nblk, TB, 0, stream>>>(out, N);
}

// Round 10
// 924.570 us; speedup vs baseline: 2.0990x; 2.0990x over previous
//
#include <hip/hip_runtime.h>
#include <hip/hip_bf16.h>
#include <math.h>

// BernNet: h = relu(x@W1+b1)@W2+b2 ; out = sum_m c_m A^m h (Horner) ; log_softmax
// A = D^-1/2 Adj D^-1/2. CSR(dst) via bucketed counting sort (no per-edge global
// atomics). Horner SpMV: octet gather (8 lanes/edge, 16B) -> per-wave LDS tile ->
// ds_read_b64_tr_b16 -> mfma(ones, B) row-sum (k-permutation-invariant).
// HISTORY: nontemporal csr loads REGRESSED +195us (r6). Quarter-plane feature
// split REGRESSED 3x (r9: 4x per-node overhead + 32B-row line waste).

#define NFEAT 512
#define HIDDEN 128
#define NCLASS 64
#define KORD 10
#define MAXBUCK 1600   // LDS histogram capacity (N <= 102400)
#define CH 8192        // edges per block in bucket passes (391 blocks)

typedef unsigned short ushort_t;
typedef __attribute__((ext_vector_type(8))) short short8;
typedef __attribute__((ext_vector_type(4))) short short4v;
typedef __attribute__((ext_vector_type(4))) float f32x4;
typedef __attribute__((ext_vector_type(8))) unsigned short us8v;

static __device__ __forceinline__ float bf2f(ushort_t u) {
    return __uint_as_float(((unsigned)u) << 16);
}
static __device__ __forceinline__ ushort_t f2bf(float f) {
    __hip_bfloat16 h = __float2bfloat16(f);
    return *reinterpret_cast<ushort_t*>(&h);
}
static __device__ __forceinline__ short8 pack8(float4 a, float4 b) {
    short8 r;
    r[0] = (short)f2bf(a.x); r[1] = (short)f2bf(a.y);
    r[2] = (short)f2bf(a.z); r[3] = (short)f2bf(a.w);
    r[4] = (short)f2bf(b.x); r[5] = (short)f2bf(b.y);
    r[6] = (short)f2bf(b.z); r[7] = (short)f2bf(b.w);
    return r;
}

// ---------------- graph build: bucketed counting sort ----------------

__global__ __launch_bounds__(256) void p0_hist(const int* __restrict__ src,
                                               const int* __restrict__ dst,
                                               int* __restrict__ bhist,  // [2*MAXBUCK]
                                               int E, int nbuck) {
    __shared__ int hd[MAXBUCK];
    __shared__ int hs[MAXBUCK];
    for (int i = threadIdx.x; i < nbuck; i += 256) { hd[i] = 0; hs[i] = 0; }
    __syncthreads();
    int base = blockIdx.x * CH;
    int lim = min(base + CH, E);
    for (int e = base + threadIdx.x; e < lim; e += 256) {
        atomicAdd(&hd[dst[e] >> 6], 1);
        atomicAdd(&hs[src[e] >> 6], 1);
    }
    __syncthreads();
    for (int i = threadIdx.x; i < nbuck; i += 256) {
        int v = hd[i];
        if (v) atomicAdd(&bhist[i], v);
        int w = hs[i];
        if (w) atomicAdd(&bhist[MAXBUCK + i], w);
    }
}

__global__ __launch_bounds__(256) void p_scan(const int* __restrict__ bhist,
                                              int* __restrict__ bstart,
                                              int* __restrict__ gpos,
                                              int* __restrict__ sstart,
                                              int* __restrict__ spos, int nbuck,
                                              int* __restrict__ row_ptr, int N, int E) {
    __shared__ int ws[4];
    __shared__ int carry;
    int t = threadIdx.x, lane = t & 63, w = t >> 6;
    #pragma unroll
    for (int pass = 0; pass < 2; ++pass) {
        const int* in = bhist + pass * MAXBUCK;
        int* o1 = pass ? sstart : bstart;
        int* o2 = pass ? spos : gpos;
        if (t == 0) carry = 0;
        __syncthreads();
        for (int base = 0; base < nbuck; base += 256) {
            int i = base + t;
            int v = (i < nbuck) ? in[i] : 0;
            int s = v;
            #pragma unroll
            for (int off = 1; off < 64; off <<= 1) {
                int u = __shfl_up(s, off);
                if (lane >= off) s += u;
            }
            if (lane == 63) ws[w] = s;
            __syncthreads();
            int pre = 0;
            #pragma unroll
            for (int j = 0; j < 4; ++j)
                if (j < w) pre += ws[j];
            int excl = carry + pre + s - v;
            if (i < nbuck) {
                o1[i] = excl;
                o2[i] = excl;
            }
            __syncthreads();
            if (t == 255) carry += pre + s;
            __syncthreads();
        }
        if (t == 0) o1[nbuck] = E;
        __syncthreads();
    }
    if (t == 0) row_ptr[N] = E;
}

__global__ __launch_bounds__(256) void p1_scatter(const int* __restrict__ src,
                                                  const int* __restrict__ dst,
                                                  int* __restrict__ gpos,
                                                  int* __restrict__ spos,
                                                  int* __restrict__ buf,
                                                  unsigned char* __restrict__ sbuf,
                                                  int E, int nbuck) {
    __shared__ int hd[MAXBUCK];
    __shared__ int bd[MAXBUCK];
    __shared__ int hs[MAXBUCK];
    __shared__ int bs[MAXBUCK];
    for (int i = threadIdx.x; i < nbuck; i += 256) { hd[i] = 0; hs[i] = 0; }
    __syncthreads();
    int base = blockIdx.x * CH;
    int lim = min(base + CH, E);
    for (int e = base + threadIdx.x; e < lim; e += 256) {
        atomicAdd(&hd[dst[e] >> 6], 1);
        atomicAdd(&hs[src[e] >> 6], 1);
    }
    __syncthreads();
    for (int i = threadIdx.x; i < nbuck; i += 256) {
        int v = hd[i];
        bd[i] = v ? atomicAdd(&gpos[i], v) : 0;
        hd[i] = 0;
        int u = hs[i];
        bs[i] = u ? atomicAdd(&spos[i], u) : 0;
        hs[i] = 0;
    }
    __syncthreads();
    for (int e = base + threadIdx.x; e < lim; e += 256) {
        int d = dst[e], s = src[e];
        int bk = d >> 6;
        int off = atomicAdd(&hd[bk], 1);
        buf[bd[bk] + off] = s | ((d & 63) << 17);
        int sk = s >> 6;
        int off2 = atomicAdd(&hs[sk], 1);
        sbuf[bs[sk] + off2] = (unsigned char)(s & 63);
    }
}

__global__ __launch_bounds__(256) void p2_group(const int* __restrict__ buf,
                                                const int* __restrict__ bstart,
                                                int* __restrict__ csr,
                                                int* __restrict__ row_ptr, int N) {
    int bk = blockIdx.x;
    int s0 = bstart[bk], s1 = bstart[bk + 1];
    __shared__ int cnt[64];
    __shared__ int pos[64];
    int t = threadIdx.x;
    if (t < 64) cnt[t] = 0;
    __syncthreads();
    for (int i = s0 + t; i < s1; i += 256) atomicAdd(&cnt[buf[i] >> 17], 1);
    __syncthreads();
    if (t < 64) {
        int v = cnt[t], s = v;
        #pragma unroll
        for (int off = 1; off < 64; off <<= 1) {
            int u = __shfl_up(s, off);
            if (t >= off) s += u;
        }
        int excl = s - v;
        int node = bk * 64 + t;
        if (node < N) row_ptr[node] = s0 + excl;
        pos[t] = s0 + excl;
    }
    __syncthreads();
    for (int i = s0 + t; i < s1; i += 256) {
        int p = buf[i];
        int off = atomicAdd(&pos[p >> 17], 1);
        csr[off] = p & 0x1FFFF;
    }
}

__global__ __launch_bounds__(256) void p2b_deg(const unsigned char* __restrict__ sbuf,
                                               const int* __restrict__ sstart,
                                               float* __restrict__ dinv, int N) {
    int bk = blockIdx.x;
    int s0 = sstart[bk], s1 = sstart[bk + 1];
    __shared__ int cnt[64];
    int t = threadIdx.x;
    if (t < 64) cnt[t] = 0;
    __syncthreads();
    for (int i = s0 + t; i < s1; i += 256) atomicAdd(&cnt[sbuf[i]], 1);
    __syncthreads();
    if (t < 64) {
        int node = bk * 64 + t;
        if (node < N) {
            int d = cnt[t];
            dinv[node] = (d > 0) ? rsqrtf((float)d) : 0.0f;
        }
    }
}

// ---------------- Bernstein coefficients ----------------

__global__ void k_coef(const float* __restrict__ temp, float* __restrict__ c,
                       float* __restrict__ temp_out) {
    if (threadIdx.x != 0 || blockIdx.x != 0) return;
    float T[KORD + 1];
    #pragma unroll
    for (int j = 0; j <= KORD; ++j) {
        T[j] = fmaxf(temp[j], 0.0f);
        temp_out[j] = T[j];
    }
    float binom[KORD + 1][KORD + 1];
    for (int n = 0; n <= KORD; ++n) {
        binom[n][0] = 1.0f;
        for (int k = 1; k <= n; ++k)
            binom[n][k] = (k == n) ? 1.0f : binom[n - 1][k - 1] + binom[n - 1][k];
        for (int k = n + 1; k <= KORD; ++k) binom[n][k] = 0.0f;
    }
    for (int m = 0; m <= KORD; ++m) {
        float s = 0.0f;
        for (int j = 0; j <= KORD; ++j) {
            float cj = 0.0f;
            for (int p = 0; p <= j && p <= m; ++p) {
                int q = m - p;
                if (q > KORD - j) continue;
                float t = binom[j][p] * binom[KORD - j][q];
                cj += (p & 1) ? -t : t;
            }
            s += binom[KORD][j] * T[j] * cj;
        }
        c[m] = s * (1.0f / 1024.0f);
    }
}

// ---------------- weight prep: transpose + bf16 ----------------

__global__ void k_prepw(const float* __restrict__ W1, const float* __restrict__ W2,
                        ushort_t* __restrict__ W1t, ushort_t* __restrict__ W2t) {
    int id = blockIdx.x * blockDim.x + threadIdx.x;
    if (id < HIDDEN * NFEAT) {
        int n = id / NFEAT, k = id % NFEAT;
        W1t[id] = f2bf(W1[(size_t)k * HIDDEN + n]);
    } else if (id < HIDDEN * NFEAT + NCLASS * HIDDEN) {
        int j = id - HIDDEN * NFEAT;
        int n = j / HIDDEN, k = j % HIDDEN;
        W2t[j] = f2bf(W2[(size_t)k * NCLASS + n]);
    }
}

// ---------------- GEMM1: h1 = relu(x @ W1 + b1), bf16 MFMA ----------------

__global__ __launch_bounds__(256) void gemm1(const float* __restrict__ x,
                                             const ushort_t* __restrict__ W1t,
                                             const float* __restrict__ b1,
                                             ushort_t* __restrict__ h1, int M) {
    __shared__ char smem[24576];
    char* As = smem;
    char* Bs = smem + 8192;
    const int t = threadIdx.x;
    const int m0 = blockIdx.x * 64;
    const int wid = t >> 6, lane = t & 63;
    const int wr = wid >> 1, wc = wid & 1;
    const int lm = lane & 15, lg = lane >> 4;

    f32x4 acc[2][4];
    #pragma unroll
    for (int i = 0; i < 2; ++i)
        #pragma unroll
        for (int j = 0; j < 4; ++j) acc[i][j] = (f32x4){0.f, 0.f, 0.f, 0.f};

    for (int k0 = 0; k0 < NFEAT; k0 += 64) {
        #pragma unroll
        for (int i = 0; i < 2; ++i) {
            int idx = t + i * 256;
            int r = idx >> 3, c8 = idx & 7;
            float4 v0 = make_float4(0.f, 0.f, 0.f, 0.f), v1 = v0;
            if (m0 + r < M) {
                const float* p = &x[(size_t)(m0 + r) * NFEAT + k0 + c8 * 8];
                v0 = *(const float4*)p;
                v1 = *(const float4*)(p + 4);
            }
            *(short8*)(As + r * 128 + ((c8 * 16) ^ ((r & 7) << 4))) = pack8(v0, v1);
        }
        #pragma unroll
        for (int i = 0; i < 4; ++i) {
            int idx = t + i * 256;
            int r = idx >> 3, c8 = idx & 7;
            short8 v = *(const short8*)&W1t[(size_t)r * NFEAT + k0 + c8 * 8];
            *(short8*)(Bs + r * 128 + ((c8 * 16) ^ ((r & 7) << 4))) = v;
        }
        __syncthreads();
        #pragma unroll
        for (int kk = 0; kk < 64; kk += 32) {
            int kb = (kk + lg * 8) * 2;
            short8 af[2], bfr[4];
            #pragma unroll
            for (int fi = 0; fi < 2; ++fi) {
                int m = wr * 32 + fi * 16 + lm;
                af[fi] = *(const short8*)(As + m * 128 + (kb ^ ((m & 7) << 4)));
            }
            #pragma unroll
            for (int fj = 0; fj < 4; ++fj) {
                int n = wc * 64 + fj * 16 + lm;
                bfr[fj] = *(const short8*)(Bs + n * 128 + (kb ^ ((n & 7) << 4)));
            }
            #pragma unroll
            for (int fi = 0; fi < 2; ++fi)
                #pragma unroll
                for (int fj = 0; fj < 4; ++fj)
                    acc[fi][fj] = __builtin_amdgcn_mfma_f32_16x16x32_bf16(
                        af[fi], bfr[fj], acc[fi][fj], 0, 0, 0);
        }
        __syncthreads();
    }

    ushort_t* Cs = (ushort_t*)smem;
    #pragma unroll
    for (int fi = 0; fi < 2; ++fi)
        #pragma unroll
        for (int fj = 0; fj < 4; ++fj) {
            int col = wc * 64 + fj * 16 + lm;
            float bb = b1[col];
            #pragma unroll
            for (int q = 0; q < 4; ++q) {
                int r = wr * 32 + fi * 16 + lg * 4 + q;
                float z = fmaxf(acc[fi][fj][q] + bb, 0.0f);
                Cs[r * 128 + col] = f2bf(z);
            }
        }
    __syncthreads();
    #pragma unroll
    for (int i = 0; i < 4; ++i) {
        int idx = t + i * 256;
        int r = idx >> 4, c8 = idx & 15;
        if (m0 + r < M)
            *(short8*)&h1[(size_t)(m0 + r) * HIDDEN + c8 * 8] =
                *(const short8*)&Cs[r * 128 + c8 * 8];
    }
}

// ---------------- GEMM2: h = h1 @ W2 + b2 ; emits hb=bf16(h), g0=bf16(dinv*cK*h) ----

__global__ __launch_bounds__(256) void gemm2(const ushort_t* __restrict__ h1,
                                             const ushort_t* __restrict__ W2t,
                                             const float* __restrict__ b2,
                                             const float* __restrict__ dinv,
                                             const float* __restrict__ c,
                                             ushort_t* __restrict__ hb,
                                             ushort_t* __restrict__ g0, int M) {
    __shared__ char smem[49152];
    char* As = smem;
    char* Bs = smem + 32768;
    const int t = threadIdx.x;
    const int m0 = blockIdx.x * 128;
    const int wr = t >> 6, lane = t & 63;
    const int lm = lane & 15, lg = lane >> 4;

    #pragma unroll
    for (int i = 0; i < 8; ++i) {
        int idx = t + i * 256;
        int r = idx >> 4, c8 = idx & 15;
        short8 v = (short8){0, 0, 0, 0, 0, 0, 0, 0};
        if (m0 + r < M) v = *(const short8*)&h1[(size_t)(m0 + r) * HIDDEN + c8 * 8];
        *(short8*)(As + r * 256 + ((c8 * 16) ^ ((r & 7) << 4))) = v;
    }
    #pragma unroll
    for (int i = 0; i < 4; ++i) {
        int idx = t + i * 256;
        int r = idx >> 4, c8 = idx & 15;
        short8 v = *(const short8*)&W2t[(size_t)r * HIDDEN + c8 * 8];
        *(short8*)(Bs + r * 256 + ((c8 * 16) ^ ((r & 7) << 4))) = v;
    }
    __syncthreads();

    f32x4 acc[2][4];
    #pragma unroll
    for (int i = 0; i < 2; ++i)
        #pragma unroll
        for (int j = 0; j < 4; ++j) acc[i][j] = (f32x4){0.f, 0.f, 0.f, 0.f};

    #pragma unroll
    for (int kk = 0; kk < HIDDEN; kk += 32) {
        int kb = (kk + lg * 8) * 2;
        short8 af[2], bfr[4];
        #pragma unroll
        for (int fi = 0; fi < 2; ++fi) {
            int m = wr * 32 + fi * 16 + lm;
            af[fi] = *(const short8*)(As + m * 256 + (kb ^ ((m & 7) << 4)));
        }
        #pragma unroll
        for (int fj = 0; fj < 4; ++fj) {
            int n = fj * 16 + lm;
            bfr[fj] = *(const short8*)(Bs + n * 256 + (kb ^ ((n & 7) << 4)));
        }
        #pragma unroll
        for (int fi = 0; fi < 2; ++fi)
            #pragma unroll
            for (int fj = 0; fj < 4; ++fj)
                acc[fi][fj] = __builtin_amdgcn_mfma_f32_16x16x32_bf16(
                    af[fi], bfr[fj], acc[fi][fj], 0, 0, 0);
    }

    float cK = c[KORD];
    #pragma unroll
    for (int fi = 0; fi < 2; ++fi)
        #pragma unroll
        for (int q = 0; q < 4; ++q) {
            int r = m0 + wr * 32 + fi * 16 + lg * 4 + q;
            if (r < M) {
                float dv = dinv[r];
                #pragma unroll
                for (int fj = 0; fj < 4; ++fj) {
                    int col = fj * 16 + lm;
                    float z = acc[fi][fj][q] + b2[col];
                    size_t o = (size_t)r * NCLASS + col;
                    hb[o] = f2bf(z);
                    g0[o] = f2bf(dv * cK * z);
                }
            }
        }
}

// ---------------- Horner SpMV step via MFMA row-sum ----------------
// Per node (1 wave): stage 32 gathered rows [128B] into per-wave LDS as 4 tiles
// [32 k][16 n] (stride 1056B for 16B-aligned b128 writes), tr-read B-fragments,
// acc = mfma(ones, B, acc). C[m][n] = sum_k B[k][n] (k-permutation-invariant).
// Epilogue: lane l owns feature l (col=l&15, tile=l>>4).

__global__ __launch_bounds__(256) void k_adj(const ushort_t* __restrict__ gin,
                                             const ushort_t* __restrict__ hb,
                                             const float* __restrict__ dinv,
                                             const int* __restrict__ row_ptr,
                                             const int* __restrict__ csr,
                                             const float* __restrict__ c, int cidx,
                                             ushort_t* __restrict__ gout,
                                             float* __restrict__ out, int last, int N) {
    __shared__ char smem[4 * 4224];  // 4 waves x (4 tiles x 1056B)
    const int wv = threadIdx.x >> 6;
    const int wid = blockIdx.x * 4 + wv;
    const int lane = threadIdx.x & 63;
    if (wid >= N) return;
    char* wbase = smem + wv * 4224;

    const int g = lane >> 3;              // edge slot within 8-group
    const int f0 = (lane & 7) * 8;        // feature base of this lane's 16B gather
    char* stg = wbase + (f0 >> 4) * 1056 + (f0 & 15) * 2;  // + k*32 at use
    // tr per-lane addr: col=(l&15), row-group base (l>>4)*8 rows (8 rows = 256B)
    unsigned traddr = (unsigned)(size_t)wbase +
                      (unsigned)((lane & 15) * 2 + (lane >> 4) * 256);

    int b = row_ptr[wid], e = row_ptr[wid + 1];

    short8 ones;
    #pragma unroll
    for (int p = 0; p < 8; ++p) ones[p] = (short)0x3F80;  // bf16 1.0

    f32x4 acc0 = {0.f, 0.f, 0.f, 0.f}, acc1 = acc0, acc2 = acc0, acc3 = acc0;

    for (int i = b; i < e; i += 32) {
        #pragma unroll
        for (int u = 0; u < 4; ++u) {
            int ei = i + u * 8 + g;
            us8v v = (us8v){0, 0, 0, 0, 0, 0, 0, 0};
            if (ei < e) {
                int s2 = csr[ei];
                v = *(const us8v*)&gin[(size_t)s2 * NCLASS + f0];
            }
            *(us8v*)(stg + (u * 8 + g) * 32) = v;
        }
        short4v lo0, hi0, lo1, hi1, lo2, hi2, lo3, hi3;
        asm volatile(
            "ds_read_b64_tr_b16 %0, %8\n\t"
            "ds_read_b64_tr_b16 %1, %8 offset:128\n\t"
            "ds_read_b64_tr_b16 %2, %8 offset:1056\n\t"
            "ds_read_b64_tr_b16 %3, %8 offset:1184\n\t"
            "ds_read_b64_tr_b16 %4, %8 offset:2112\n\t"
            "ds_read_b64_tr_b16 %5, %8 offset:2240\n\t"
            "ds_read_b64_tr_b16 %6, %8 offset:3168\n\t"
            "ds_read_b64_tr_b16 %7, %8 offset:3296\n\t"
            "s_waitcnt lgkmcnt(0)"
            : "=&v"(lo0), "=&v"(hi0), "=&v"(lo1), "=&v"(hi1),
              "=&v"(lo2), "=&v"(hi2), "=&v"(lo3), "=&v"(hi3)
            : "v"(traddr)
            : "memory");
        __builtin_amdgcn_sched_barrier(0);
        short8 b0, b1, b2, b3;
        #pragma unroll
        for (int p = 0; p < 4; ++p) {
            b0[p] = lo0[p]; b0[p + 4] = hi0[p];
            b1[p] = lo1[p]; b1[p + 4] = hi1[p];
            b2[p] = lo2[p]; b2[p + 4] = hi2[p];
            b3[p] = lo3[p]; b3[p + 4] = hi3[p];
        }
        acc0 = __builtin_amdgcn_mfma_f32_16x16x32_bf16(ones, b0, acc0, 0, 0, 0);
        acc1 = __builtin_amdgcn_mfma_f32_16x16x32_bf16(ones, b1, acc1, 0, 0, 0);
        acc2 = __builtin_amdgcn_mfma_f32_16x16x32_bf16(ones, b2, acc2, 0, 0, 0);
        acc3 = __builtin_amdgcn_mfma_f32_16x16x32_bf16(ones, b3, acc3, 0, 0, 0);
    }

    // lane l -> feature l: tile = l>>4 (C rows all equal; take reg 0)
    float v = (lane < 16) ? acc0[0] : (lane < 32) ? acc1[0]
            : (lane < 48) ? acc2[0] : acc3[0];
    float dv = dinv[wid];
    float cc = c[cidx];
    size_t o = (size_t)wid * NCLASS + lane;
    float w = dv * v + cc * bf2f(hb[o]);

    if (!last) {
        gout[o] = f2bf(dv * w);
    } else {
        float mx = w;
        #pragma unroll
        for (int off = 32; off >= 1; off >>= 1) mx = fmaxf(mx, __shfl_xor(mx, off));
        float ex = expf(w - mx), s = ex;
        #pragma unroll
        for (int off = 32; off >= 1; off >>= 1) s += __shfl_xor(s, off);
        out[o] = w - mx - logf(s);
    }
}

// ---------------- launch ----------------

extern "C" void kernel_launch(void* const* d_in, const int* in_sizes, int n_in,
                              void* d_out, int out_size, void* d_ws, size_t ws_size,
                              hipStream_t stream) {
    const float* x = (const float*)d_in[0];
    const int* ei = (const int*)d_in[1];
    const float* W1 = (const float*)d_in[2];
    const float* b1 = (const float*)d_in[3];
    const float* W2 = (const float*)d_in[4];
    const float* b2 = (const float*)d_in[5];
    const float* temp = (const float*)d_in[6];

    const int N = in_sizes[0] / NFEAT;  // 100000
    const int E = in_sizes[1] / 2;      // 3200000
    const int* src = ei;
    const int* dst = ei + E;
    const int nbuck = (N + 63) >> 6;    // 1563

    float* out = (float*)d_out;
    float* temp_out = out + (size_t)N * NCLASS;

    char* ws = (char*)d_ws;
    size_t off = 0;
    auto alloc = [&](size_t bytes) {
        char* p = ws + off;
        off = (off + bytes + 255) & ~(size_t)255;
        return p;
    };
    ushort_t* h1 = (ushort_t*)alloc((size_t)N * HIDDEN * sizeof(ushort_t));  // 25.6MB
    ushort_t* hb = (ushort_t*)alloc((size_t)N * NCLASS * sizeof(ushort_t));
    ushort_t* gA = (ushort_t*)alloc((size_t)N * NCLASS * sizeof(ushort_t));
    ushort_t* gB = (ushort_t*)alloc((size_t)N * NCLASS * sizeof(ushort_t));
    float* dinv = (float*)alloc((size_t)N * sizeof(float));
    int* row_ptr = (int*)alloc((size_t)(N + 1) * sizeof(int));
    int* bhist = (int*)alloc((size_t)(2 * MAXBUCK) * sizeof(int));
    int* bstart = (int*)alloc((size_t)(MAXBUCK + 1) * sizeof(int));
    int* gpos = (int*)alloc((size_t)MAXBUCK * sizeof(int));
    int* sstart = (int*)alloc((size_t)(MAXBUCK + 1) * sizeof(int));
    int* spos = (int*)alloc((size_t)MAXBUCK * sizeof(int));
    int* csr = (int*)alloc((size_t)E * sizeof(int));
    ushort_t* W1t = (ushort_t*)alloc((size_t)HIDDEN * NFEAT * sizeof(ushort_t));
    ushort_t* W2t = (ushort_t*)alloc((size_t)NCLASS * HIDDEN * sizeof(ushort_t));
    float* c = (float*)alloc(64);
    (void)ws_size;

    // scratch aliased onto h1 (dead until gemm1): buf 12.8MB + sbuf 3.2MB < 25.6MB
    int* buf = (int*)h1;
    unsigned char* sbuf = (unsigned char*)h1 + (size_t)13 * 1024 * 1024;

    const int TB = 256;
    const int eg = (E + CH - 1) / CH;  // 391
    const int wgrid = (N + 3) / 4;

    hipMemsetAsync(bhist, 0, (size_t)(2 * MAXBUCK) * sizeof(int), stream);
    p0_hist<<<eg, TB, 0, stream>>>(src, dst, bhist, E, nbuck);
    p_scan<<<1, TB, 0, stream>>>(bhist, bstart, gpos, sstart, spos, nbuck, row_ptr, N, E);
    p1_scatter<<<eg, TB, 0, stream>>>(src, dst, gpos, spos, buf, sbuf, E, nbuck);
    p2_group<<<nbuck, TB, 0, stream>>>(buf, bstart, csr, row_ptr, N);
    p2b_deg<<<nbuck, TB, 0, stream>>>(sbuf, sstart, dinv, N);

    k_coef<<<1, 64, 0, stream>>>(temp, c, temp_out);
    k_prepw<<<(HIDDEN * NFEAT + NCLASS * HIDDEN + TB - 1) / TB, TB, 0, stream>>>(W1, W2, W1t, W2t);

    gemm1<<<(N + 63) / 64, TB, 0, stream>>>(x, W1t, b1, h1, N);
    gemm2<<<(N + 127) / 128, TB, 0, stream>>>(h1, W2t, b2, dinv, c, hb, gA, N);

    const ushort_t* gin = gA;
    ushort_t* gout = gB;
    for (int s = 1; s <= KORD; ++s) {
        int last = (s == KORD) ? 1 : 0;
        k_adj<<<wgrid, TB, 0, stream>>>(gin, hb, dinv, row_ptr, csr, c, KORD - s,
                                        gout, out, last, N);
        const ushort_t* tmp = gin;
        gin = gout;
        gout = (ushort_t*)tmp;
    }
}

// Round 11
// 870.218 us; speedup vs baseline: 2.2301x; 1.0625x over previous
//
#include <hip/hip_runtime.h>
#include <hip/hip_bf16.h>
#include <math.h>

// BernNet: h = relu(x@W1+b1)@W2+b2 ; out = sum_m c_m A^m h (Horner) ; log_softmax
// A = D^-1/2 Adj D^-1/2. CSR(dst) via bucketed counting sort (no per-edge global
// atomics). Horner SpMV: octet gather (8 lanes/edge, 16B), TWO nodes per wave
// interleaved for 8 in-flight gathers.
// HISTORY: nontemporal csr loads REGRESSED +195us (r6). Quarter-plane feature
// split REGRESSED 3x (r9). MFMA row-sum via LDS+tr_read REGRESSED +82us (r10:
// serial LDS round-trip per iter; gathers are the critical path, not VALU).

#define NFEAT 512
#define HIDDEN 128
#define NCLASS 64
#define KORD 10
#define MAXBUCK 1600   // LDS histogram capacity (N <= 102400)
#define CH 8192        // edges per block in bucket passes (391 blocks)

typedef unsigned short ushort_t;
typedef __attribute__((ext_vector_type(8))) short short8;
typedef __attribute__((ext_vector_type(4))) float f32x4;
typedef __attribute__((ext_vector_type(8))) unsigned short us8v;

static __device__ __forceinline__ float bf2f(ushort_t u) {
    return __uint_as_float(((unsigned)u) << 16);
}
static __device__ __forceinline__ ushort_t f2bf(float f) {
    __hip_bfloat16 h = __float2bfloat16(f);
    return *reinterpret_cast<ushort_t*>(&h);
}
static __device__ __forceinline__ short8 pack8(float4 a, float4 b) {
    short8 r;
    r[0] = (short)f2bf(a.x); r[1] = (short)f2bf(a.y);
    r[2] = (short)f2bf(a.z); r[3] = (short)f2bf(a.w);
    r[4] = (short)f2bf(b.x); r[5] = (short)f2bf(b.y);
    r[6] = (short)f2bf(b.z); r[7] = (short)f2bf(b.w);
    return r;
}

// ---------------- graph build: bucketed counting sort ----------------

__global__ __launch_bounds__(256) void p0_hist(const int* __restrict__ src,
                                               const int* __restrict__ dst,
                                               int* __restrict__ bhist,  // [2*MAXBUCK]
                                               int E, int nbuck) {
    __shared__ int hd[MAXBUCK];
    __shared__ int hs[MAXBUCK];
    for (int i = threadIdx.x; i < nbuck; i += 256) { hd[i] = 0; hs[i] = 0; }
    __syncthreads();
    int base = blockIdx.x * CH;
    int lim = min(base + CH, E);
    for (int e = base + threadIdx.x; e < lim; e += 256) {
        atomicAdd(&hd[dst[e] >> 6], 1);
        atomicAdd(&hs[src[e] >> 6], 1);
    }
    __syncthreads();
    for (int i = threadIdx.x; i < nbuck; i += 256) {
        int v = hd[i];
        if (v) atomicAdd(&bhist[i], v);
        int w = hs[i];
        if (w) atomicAdd(&bhist[MAXBUCK + i], w);
    }
}

__global__ __launch_bounds__(256) void p_scan(const int* __restrict__ bhist,
                                              int* __restrict__ bstart,
                                              int* __restrict__ gpos,
                                              int* __restrict__ sstart,
                                              int* __restrict__ spos, int nbuck,
                                              int* __restrict__ row_ptr, int N, int E) {
    __shared__ int ws[4];
    __shared__ int carry;
    int t = threadIdx.x, lane = t & 63, w = t >> 6;
    #pragma unroll
    for (int pass = 0; pass < 2; ++pass) {
        const int* in = bhist + pass * MAXBUCK;
        int* o1 = pass ? sstart : bstart;
        int* o2 = pass ? spos : gpos;
        if (t == 0) carry = 0;
        __syncthreads();
        for (int base = 0; base < nbuck; base += 256) {
            int i = base + t;
            int v = (i < nbuck) ? in[i] : 0;
            int s = v;
            #pragma unroll
            for (int off = 1; off < 64; off <<= 1) {
                int u = __shfl_up(s, off);
                if (lane >= off) s += u;
            }
            if (lane == 63) ws[w] = s;
            __syncthreads();
            int pre = 0;
            #pragma unroll
            for (int j = 0; j < 4; ++j)
                if (j < w) pre += ws[j];
            int excl = carry + pre + s - v;
            if (i < nbuck) {
                o1[i] = excl;
                o2[i] = excl;
            }
            __syncthreads();
            if (t == 255) carry += pre + s;
            __syncthreads();
        }
        if (t == 0) o1[nbuck] = E;
        __syncthreads();
    }
    if (t == 0) row_ptr[N] = E;
}

__global__ __launch_bounds__(256) void p1_scatter(const int* __restrict__ src,
                                                  const int* __restrict__ dst,
                                                  int* __restrict__ gpos,
                                                  int* __restrict__ spos,
                                                  int* __restrict__ buf,
                                                  unsigned char* __restrict__ sbuf,
                                                  int E, int nbuck) {
    __shared__ int hd[MAXBUCK];
    __shared__ int bd[MAXBUCK];
    __shared__ int hs[MAXBUCK];
    __shared__ int bs[MAXBUCK];
    for (int i = threadIdx.x; i < nbuck; i += 256) { hd[i] = 0; hs[i] = 0; }
    __syncthreads();
    int base = blockIdx.x * CH;
    int lim = min(base + CH, E);
    for (int e = base + threadIdx.x; e < lim; e += 256) {
        atomicAdd(&hd[dst[e] >> 6], 1);
        atomicAdd(&hs[src[e] >> 6], 1);
    }
    __syncthreads();
    for (int i = threadIdx.x; i < nbuck; i += 256) {
        int v = hd[i];
        bd[i] = v ? atomicAdd(&gpos[i], v) : 0;
        hd[i] = 0;
        int u = hs[i];
        bs[i] = u ? atomicAdd(&spos[i], u) : 0;
        hs[i] = 0;
    }
    __syncthreads();
    for (int e = base + threadIdx.x; e < lim; e += 256) {
        int d = dst[e], s = src[e];
        int bk = d >> 6;
        int off = atomicAdd(&hd[bk], 1);
        buf[bd[bk] + off] = s | ((d & 63) << 17);
        int sk = s >> 6;
        int off2 = atomicAdd(&hs[sk], 1);
        sbuf[bs[sk] + off2] = (unsigned char)(s & 63);
    }
}

__global__ __launch_bounds__(256) void p2_group(const int* __restrict__ buf,
                                                const int* __restrict__ bstart,
                                                int* __restrict__ csr,
                                                int* __restrict__ row_ptr, int N) {
    int bk = blockIdx.x;
    int s0 = bstart[bk], s1 = bstart[bk + 1];
    __shared__ int cnt[64];
    __shared__ int pos[64];
    int t = threadIdx.x;
    if (t < 64) cnt[t] = 0;
    __syncthreads();
    for (int i = s0 + t; i < s1; i += 256) atomicAdd(&cnt[buf[i] >> 17], 1);
    __syncthreads();
    if (t < 64) {
        int v = cnt[t], s = v;
        #pragma unroll
        for (int off = 1; off < 64; off <<= 1) {
            int u = __shfl_up(s, off);
            if (t >= off) s += u;
        }
        int excl = s - v;
        int node = bk * 64 + t;
        if (node < N) row_ptr[node] = s0 + excl;
        pos[t] = s0 + excl;
    }
    __syncthreads();
    for (int i = s0 + t; i < s1; i += 256) {
        int p = buf[i];
        int off = atomicAdd(&pos[p >> 17], 1);
        csr[off] = p & 0x1FFFF;
    }
}

__global__ __launch_bounds__(256) void p2b_deg(const unsigned char* __restrict__ sbuf,
                                               const int* __restrict__ sstart,
                                               float* __restrict__ dinv, int N) {
    int bk = blockIdx.x;
    int s0 = sstart[bk], s1 = sstart[bk + 1];
    __shared__ int cnt[64];
    int t = threadIdx.x;
    if (t < 64) cnt[t] = 0;
    __syncthreads();
    for (int i = s0 + t; i < s1; i += 256) atomicAdd(&cnt[sbuf[i]], 1);
    __syncthreads();
    if (t < 64) {
        int node = bk * 64 + t;
        if (node < N) {
            int d = cnt[t];
            dinv[node] = (d > 0) ? rsqrtf((float)d) : 0.0f;
        }
    }
}

// ---------------- Bernstein coefficients ----------------

__global__ void k_coef(const float* __restrict__ temp, float* __restrict__ c,
                       float* __restrict__ temp_out) {
    if (threadIdx.x != 0 || blockIdx.x != 0) return;
    float T[KORD + 1];
    #pragma unroll
    for (int j = 0; j <= KORD; ++j) {
        T[j] = fmaxf(temp[j], 0.0f);
        temp_out[j] = T[j];
    }
    float binom[KORD + 1][KORD + 1];
    for (int n = 0; n <= KORD; ++n) {
        binom[n][0] = 1.0f;
        for (int k = 1; k <= n; ++k)
            binom[n][k] = (k == n) ? 1.0f : binom[n - 1][k - 1] + binom[n - 1][k];
        for (int k = n + 1; k <= KORD; ++k) binom[n][k] = 0.0f;
    }
    for (int m = 0; m <= KORD; ++m) {
        float s = 0.0f;
        for (int j = 0; j <= KORD; ++j) {
            float cj = 0.0f;
            for (int p = 0; p <= j && p <= m; ++p) {
                int q = m - p;
                if (q > KORD - j) continue;
                float t = binom[j][p] * binom[KORD - j][q];
                cj += (p & 1) ? -t : t;
            }
            s += binom[KORD][j] * T[j] * cj;
        }
        c[m] = s * (1.0f / 1024.0f);
    }
}

// ---------------- weight prep: transpose + bf16 ----------------

__global__ void k_prepw(const float* __restrict__ W1, const float* __restrict__ W2,
                        ushort_t* __restrict__ W1t, ushort_t* __restrict__ W2t) {
    int id = blockIdx.x * blockDim.x + threadIdx.x;
    if (id < HIDDEN * NFEAT) {
        int n = id / NFEAT, k = id % NFEAT;
        W1t[id] = f2bf(W1[(size_t)k * HIDDEN + n]);
    } else if (id < HIDDEN * NFEAT + NCLASS * HIDDEN) {
        int j = id - HIDDEN * NFEAT;
        int n = j / HIDDEN, k = j % HIDDEN;
        W2t[j] = f2bf(W2[(size_t)k * NCLASS + n]);
    }
}

// ---------------- GEMM1: h1 = relu(x @ W1 + b1), bf16 MFMA ----------------

__global__ __launch_bounds__(256) void gemm1(const float* __restrict__ x,
                                             const ushort_t* __restrict__ W1t,
                                             const float* __restrict__ b1,
                                             ushort_t* __restrict__ h1, int M) {
    __shared__ char smem[24576];
    char* As = smem;
    char* Bs = smem + 8192;
    const int t = threadIdx.x;
    const int m0 = blockIdx.x * 64;
    const int wid = t >> 6, lane = t & 63;
    const int wr = wid >> 1, wc = wid & 1;
    const int lm = lane & 15, lg = lane >> 4;

    f32x4 acc[2][4];
    #pragma unroll
    for (int i = 0; i < 2; ++i)
        #pragma unroll
        for (int j = 0; j < 4; ++j) acc[i][j] = (f32x4){0.f, 0.f, 0.f, 0.f};

    for (int k0 = 0; k0 < NFEAT; k0 += 64) {
        #pragma unroll
        for (int i = 0; i < 2; ++i) {
            int idx = t + i * 256;
            int r = idx >> 3, c8 = idx & 7;
            float4 v0 = make_float4(0.f, 0.f, 0.f, 0.f), v1 = v0;
            if (m0 + r < M) {
                const float* p = &x[(size_t)(m0 + r) * NFEAT + k0 + c8 * 8];
                v0 = *(const float4*)p;
                v1 = *(const float4*)(p + 4);
            }
            *(short8*)(As + r * 128 + ((c8 * 16) ^ ((r & 7) << 4))) = pack8(v0, v1);
        }
        #pragma unroll
        for (int i = 0; i < 4; ++i) {
            int idx = t + i * 256;
            int r = idx >> 3, c8 = idx & 7;
            short8 v = *(const short8*)&W1t[(size_t)r * NFEAT + k0 + c8 * 8];
            *(short8*)(Bs + r * 128 + ((c8 * 16) ^ ((r & 7) << 4))) = v;
        }
        __syncthreads();
        #pragma unroll
        for (int kk = 0; kk < 64; kk += 32) {
            int kb = (kk + lg * 8) * 2;
            short8 af[2], bfr[4];
            #pragma unroll
            for (int fi = 0; fi < 2; ++fi) {
                int m = wr * 32 + fi * 16 + lm;
                af[fi] = *(const short8*)(As + m * 128 + (kb ^ ((m & 7) << 4)));
            }
            #pragma unroll
            for (int fj = 0; fj < 4; ++fj) {
                int n = wc * 64 + fj * 16 + lm;
                bfr[fj] = *(const short8*)(Bs + n * 128 + (kb ^ ((n & 7) << 4)));
            }
            #pragma unroll
            for (int fi = 0; fi < 2; ++fi)
                #pragma unroll
                for (int fj = 0; fj < 4; ++fj)
                    acc[fi][fj] = __builtin_amdgcn_mfma_f32_16x16x32_bf16(
                        af[fi], bfr[fj], acc[fi][fj], 0, 0, 0);
        }
        __syncthreads();
    }

    ushort_t* Cs = (ushort_t*)smem;
    #pragma unroll
    for (int fi = 0; fi < 2; ++fi)
        #pragma unroll
        for (int fj = 0; fj < 4; ++fj) {
            int col = wc * 64 + fj * 16 + lm;
            float bb = b1[col];
            #pragma unroll
            for (int q = 0; q < 4; ++q) {
                int r = wr * 32 + fi * 16 + lg * 4 + q;
                float z = fmaxf(acc[fi][fj][q] + bb, 0.0f);
                Cs[r * 128 + col] = f2bf(z);
            }
        }
    __syncthreads();
    #pragma unroll
    for (int i = 0; i < 4; ++i) {
        int idx = t + i * 256;
        int r = idx >> 4, c8 = idx & 15;
        if (m0 + r < M)
            *(short8*)&h1[(size_t)(m0 + r) * HIDDEN + c8 * 8] =
                *(const short8*)&Cs[r * 128 + c8 * 8];
    }
}

// ---------------- GEMM2: h = h1 @ W2 + b2 ; emits hb=bf16(h), g0=bf16(dinv*cK*h) ----

__global__ __launch_bounds__(256) void gemm2(const ushort_t* __restrict__ h1,
                                             const ushort_t* __restrict__ W2t,
                                             const float* __restrict__ b2,
                                             const float* __restrict__ dinv,
                                             const float* __restrict__ c,
                                             ushort_t* __restrict__ hb,
                                             ushort_t* __restrict__ g0, int M) {
    __shared__ char smem[49152];
    char* As = smem;
    char* Bs = smem + 32768;
    const int t = threadIdx.x;
    const int m0 = blockIdx.x * 128;
    const int wr = t >> 6, lane = t & 63;
    const int lm = lane & 15, lg = lane >> 4;

    #pragma unroll
    for (int i = 0; i < 8; ++i) {
        int idx = t + i * 256;
        int r = idx >> 4, c8 = idx & 15;
        short8 v = (short8){0, 0, 0, 0, 0, 0, 0, 0};
        if (m0 + r < M) v = *(const short8*)&h1[(size_t)(m0 + r) * HIDDEN + c8 * 8];
        *(short8*)(As + r * 256 + ((c8 * 16) ^ ((r & 7) << 4))) = v;
    }
    #pragma unroll
    for (int i = 0; i < 4; ++i) {
        int idx = t + i * 256;
        int r = idx >> 4, c8 = idx & 15;
        short8 v = *(const short8*)&W2t[(size_t)r * HIDDEN + c8 * 8];
        *(short8*)(Bs + r * 256 + ((c8 * 16) ^ ((r & 7) << 4))) = v;
    }
    __syncthreads();

    f32x4 acc[2][4];
    #pragma unroll
    for (int i = 0; i < 2; ++i)
        #pragma unroll
        for (int j = 0; j < 4; ++j) acc[i][j] = (f32x4){0.f, 0.f, 0.f, 0.f};

    #pragma unroll
    for (int kk = 0; kk < HIDDEN; kk += 32) {
        int kb = (kk + lg * 8) * 2;
        short8 af[2], bfr[4];
        #pragma unroll
        for (int fi = 0; fi < 2; ++fi) {
            int m = wr * 32 + fi * 16 + lm;
            af[fi] = *(const short8*)(As + m * 256 + (kb ^ ((m & 7) << 4)));
        }
        #pragma unroll
        for (int fj = 0; fj < 4; ++fj) {
            int n = fj * 16 + lm;
            bfr[fj] = *(const short8*)(Bs + n * 256 + (kb ^ ((n & 7) << 4)));
        }
        #pragma unroll
        for (int fi = 0; fi < 2; ++fi)
            #pragma unroll
            for (int fj = 0; fj < 4; ++fj)
                acc[fi][fj] = __builtin_amdgcn_mfma_f32_16x16x32_bf16(
                    af[fi], bfr[fj], acc[fi][fj], 0, 0, 0);
    }

    float cK = c[KORD];
    #pragma unroll
    for (int fi = 0; fi < 2; ++fi)
        #pragma unroll
        for (int q = 0; q < 4; ++q) {
            int r = m0 + wr * 32 + fi * 16 + lg * 4 + q;
            if (r < M) {
                float dv = dinv[r];
                #pragma unroll
                for (int fj = 0; fj < 4; ++fj) {
                    int col = fj * 16 + lm;
                    float z = acc[fi][fj][q] + b2[col];
                    size_t o = (size_t)r * NCLASS + col;
                    hb[o] = f2bf(z);
                    g0[o] = f2bf(dv * cK * z);
                }
            }
        }
}

// ---------------- Horner SpMV step: w = A*w_prev + c[cidx]*h ----------------
// octet scheme, TWO nodes per wave: 8 lanes/edge, ushort8 (16B)/lane; per iter
// 4 gathers for node A + 4 for node B in flight. g==0 lanes write row A,
// g==1 lanes write row B (256B contiguous).

__global__ __launch_bounds__(256) void k_adj(const ushort_t* __restrict__ gin,
                                             const ushort_t* __restrict__ hb,
                                             const float* __restrict__ dinv,
                                             const int* __restrict__ row_ptr,
                                             const int* __restrict__ csr,
                                             const float* __restrict__ c, int cidx,
                                             ushort_t* __restrict__ gout,
                                             float* __restrict__ out, int last, int N) {
    int wv = blockIdx.x * 4 + (threadIdx.x >> 6);
    int nA = wv * 2;
    if (nA >= N) return;
    int nB = nA + 1;
    bool hasB = nB < N;
    int lane = threadIdx.x & 63;
    const int g = lane >> 3;         // edge slot within octet (0..7)
    const int f0 = (lane & 7) * 8;   // feature base

    int bA = row_ptr[nA], eA = row_ptr[nA + 1];
    int bB = hasB ? row_ptr[nB] : 0;
    int eB = hasB ? row_ptr[nB + 1] : 0;

    float a[8] = {0.f, 0.f, 0.f, 0.f, 0.f, 0.f, 0.f, 0.f};
    float bacc[8] = {0.f, 0.f, 0.f, 0.f, 0.f, 0.f, 0.f, 0.f};
    int itA = (eA - bA + 31) >> 5;
    int itB = (eB - bB + 31) >> 5;
    int nIter = max(itA, itB);
    int iA = bA, iB = bB;
    for (int it = 0; it < nIter; ++it) {
        us8v vA[4], vB[4];
        #pragma unroll
        for (int u = 0; u < 4; ++u) {
            int ei = iA + u * 8 + g;
            vA[u] = (us8v){0, 0, 0, 0, 0, 0, 0, 0};
            if (ei < eA) vA[u] = *(const us8v*)&gin[(size_t)csr[ei] * NCLASS + f0];
        }
        #pragma unroll
        for (int u = 0; u < 4; ++u) {
            int ei = iB + u * 8 + g;
            vB[u] = (us8v){0, 0, 0, 0, 0, 0, 0, 0};
            if (ei < eB) vB[u] = *(const us8v*)&gin[(size_t)csr[ei] * NCLASS + f0];
        }
        #pragma unroll
        for (int u = 0; u < 4; ++u)
            #pragma unroll
            for (int q = 0; q < 8; ++q) {
                a[q] += bf2f(vA[u][q]);
                bacc[q] += bf2f(vB[u][q]);
            }
        iA += 32;
        iB += 32;
    }
    // combine the 8 edge-groups (lanes with equal lane&7)
    #pragma unroll
    for (int off = 8; off <= 32; off <<= 1)
        #pragma unroll
        for (int q = 0; q < 8; ++q) {
            a[q] += __shfl_xor(a[q], off);
            bacc[q] += __shfl_xor(bacc[q], off);
        }

    float cc = c[cidx];
    float dvA = dinv[nA];
    float dvB = hasB ? dinv[nB] : 0.0f;
    size_t oA = (size_t)nA * NCLASS + f0;
    size_t oB = (size_t)nB * NCLASS + f0;
    us8v hA = *(const us8v*)&hb[oA];
    us8v hB = hasB ? *(const us8v*)&hb[oB] : (us8v){0, 0, 0, 0, 0, 0, 0, 0};
    float wA[8], wB[8];
    #pragma unroll
    for (int q = 0; q < 8; ++q) {
        wA[q] = dvA * a[q] + cc * bf2f(hA[q]);
        wB[q] = dvB * bacc[q] + cc * bf2f(hB[q]);
    }

    if (!last) {
        if (g == 0) {
            us8v r;
            #pragma unroll
            for (int q = 0; q < 8; ++q) r[q] = f2bf(dvA * wA[q]);
            *(us8v*)&gout[oA] = r;
        } else if (g == 1 && hasB) {
            us8v r;
            #pragma unroll
            for (int q = 0; q < 8; ++q) r[q] = f2bf(dvB * wB[q]);
            *(us8v*)&gout[oB] = r;
        }
    } else {
        // log_softmax for node A (all 8-lane groups hold full replicas)
        float mxA = wA[0], mxB = wB[0];
        #pragma unroll
        for (int q = 1; q < 8; ++q) {
            mxA = fmaxf(mxA, wA[q]);
            mxB = fmaxf(mxB, wB[q]);
        }
        #pragma unroll
        for (int off = 4; off >= 1; off >>= 1) {
            mxA = fmaxf(mxA, __shfl_xor(mxA, off));
            mxB = fmaxf(mxB, __shfl_xor(mxB, off));
        }
        float sA = 0.f, sB = 0.f;
        #pragma unroll
        for (int q = 0; q < 8; ++q) {
            sA += expf(wA[q] - mxA);
            sB += expf(wB[q] - mxB);
        }
        #pragma unroll
        for (int off = 4; off >= 1; off >>= 1) {
            sA += __shfl_xor(sA, off);
            sB += __shfl_xor(sB, off);
        }
        float lsA = logf(sA), lsB = logf(sB);
        if (g == 0) {
            float4 r0 = make_float4(wA[0] - mxA - lsA, wA[1] - mxA - lsA,
                                    wA[2] - mxA - lsA, wA[3] - mxA - lsA);
            float4 r1 = make_float4(wA[4] - mxA - lsA, wA[5] - mxA - lsA,
                                    wA[6] - mxA - lsA, wA[7] - mxA - lsA);
            *(float4*)&out[oA] = r0;
            *(float4*)&out[oA + 4] = r1;
        } else if (g == 1 && hasB) {
            float4 r0 = make_float4(wB[0] - mxB - lsB, wB[1] - mxB - lsB,
                                    wB[2] - mxB - lsB, wB[3] - mxB - lsB);
            float4 r1 = make_float4(wB[4] - mxB - lsB, wB[5] - mxB - lsB,
                                    wB[6] - mxB - lsB, wB[7] - mxB - lsB);
            *(float4*)&out[oB] = r0;
            *(float4*)&out[oB + 4] = r1;
        }
    }
}

// ---------------- launch ----------------

extern "C" void kernel_launch(void* const* d_in, const int* in_sizes, int n_in,
                              void* d_out, int out_size, void* d_ws, size_t ws_size,
                              hipStream_t stream) {
    const float* x = (const float*)d_in[0];
    const int* ei = (const int*)d_in[1];
    const float* W1 = (const float*)d_in[2];
    const float* b1 = (const float*)d_in[3];
    const float* W2 = (const float*)d_in[4];
    const float* b2 = (const float*)d_in[5];
    const float* temp = (const float*)d_in[6];

    const int N = in_sizes[0] / NFEAT;  // 100000
    const int E = in_sizes[1] / 2;      // 3200000
    const int* src = ei;
    const int* dst = ei + E;
    const int nbuck = (N + 63) >> 6;    // 1563

    float* out = (float*)d_out;
    float* temp_out = out + (size_t)N * NCLASS;

    char* ws = (char*)d_ws;
    size_t off = 0;
    auto alloc = [&](size_t bytes) {
        char* p = ws + off;
        off = (off + bytes + 255) & ~(size_t)255;
        return p;
    };
    ushort_t* h1 = (ushort_t*)alloc((size_t)N * HIDDEN * sizeof(ushort_t));  // 25.6MB
    ushort_t* hb = (ushort_t*)alloc((size_t)N * NCLASS * sizeof(ushort_t));
    ushort_t* gA = (ushort_t*)alloc((size_t)N * NCLASS * sizeof(ushort_t));
    ushort_t* gB = (ushort_t*)alloc((size_t)N * NCLASS * sizeof(ushort_t));
    float* dinv = (float*)alloc((size_t)N * sizeof(float));
    int* row_ptr = (int*)alloc((size_t)(N + 1) * sizeof(int));
    int* bhist = (int*)alloc((size_t)(2 * MAXBUCK) * sizeof(int));
    int* bstart = (int*)alloc((size_t)(MAXBUCK + 1) * sizeof(int));
    int* gpos = (int*)alloc((size_t)MAXBUCK * sizeof(int));
    int* sstart = (int*)alloc((size_t)(MAXBUCK + 1) * sizeof(int));
    int* spos = (int*)alloc((size_t)MAXBUCK * sizeof(int));
    int* csr = (int*)alloc((size_t)E * sizeof(int));
    ushort_t* W1t = (ushort_t*)alloc((size_t)HIDDEN * NFEAT * sizeof(ushort_t));
    ushort_t* W2t = (ushort_t*)alloc((size_t)NCLASS * HIDDEN * sizeof(ushort_t));
    float* c = (float*)alloc(64);
    (void)ws_size;

    // scratch aliased onto h1 (dead until gemm1): buf 12.8MB + sbuf 3.2MB < 25.6MB
    int* buf = (int*)h1;
    unsigned char* sbuf = (unsigned char*)h1 + (size_t)13 * 1024 * 1024;

    const int TB = 256;
    const int eg = (E + CH - 1) / CH;  // 391
    const int nwaves = (N + 1) / 2;    // 2 nodes per wave
    const int wgrid = (nwaves + 3) / 4;

    hipMemsetAsync(bhist, 0, (size_t)(2 * MAXBUCK) * sizeof(int), stream);
    p0_hist<<<eg, TB, 0, stream>>>(src, dst, bhist, E, nbuck);
    p_scan<<<1, TB, 0, stream>>>(bhist, bstart, gpos, sstart, spos, nbuck, row_ptr, N, E);
    p1_scatter<<<eg, TB, 0, stream>>>(src, dst, gpos, spos, buf, sbuf, E, nbuck);
    p2_group<<<nbuck, TB, 0, stream>>>(buf, bstart, csr, row_ptr, N);
    p2b_deg<<<nbuck, TB, 0, stream>>>(sbuf, sstart, dinv, N);

    k_coef<<<1, 64, 0, stream>>>(temp, c, temp_out);
    k_prepw<<<(HIDDEN * NFEAT + NCLASS * HIDDEN + TB - 1) / TB, TB, 0, stream>>>(W1, W2, W1t, W2t);

    gemm1<<<(N + 63) / 64, TB, 0, stream>>>(x, W1t, b1, h1, N);
    gemm2<<<(N + 127) / 128, TB, 0, stream>>>(h1, W2t, b2, dinv, c, hb, gA, N);

    const ushort_t* gin = gA;
    ushort_t* gout = gB;
    for (int s = 1; s <= KORD; ++s) {
        int last = (s == KORD) ? 1 : 0;
        k_adj<<<wgrid, TB, 0, stream>>>(gin, hb, dinv, row_ptr, csr, c, KORD - s,
                                        gout, out, last, N);
        const ushort_t* tmp = gin;
        gin = gout;
        gout = (ushort_t*)tmp;
    }
}

// Round 12
// 830.565 us; speedup vs baseline: 2.3366x; 1.0477x over previous
//
#include <hip/hip_runtime.h>
#include <hip/hip_bf16.h>
#include <math.h>

// BernNet: h = relu(x@W1+b1)@W2+b2 ; out = sum_m c_m A^m h (Horner) ; log_softmax
// A = D^-1/2 Adj D^-1/2. CSR(dst) via ONE-PASS fixed-capacity bucket sort
// (2688 slots/bucket = +14sigma over Poisson(2048); no histogram pre-pass, no
// scan, no per-edge global atomics). deg via src-bucket byte sort.
// Horner SpMV: octet gather (8 lanes/edge, 16B), ONE node per wave (r7 form).
// HISTORY: nontemporal csr loads REGRESSED +195us (r6). Quarter-plane feature
// split REGRESSED 3x (r9). MFMA row-sum via LDS+tr_read REGRESSED +82us (r10).
// Two-node-per-wave interleave REGRESSED +28us (r11: +19% masked load issue).

#define NFEAT 512
#define HIDDEN 128
#define NCLASS 64
#define KORD 10
#define MAXBUCK 1600   // LDS histogram capacity (N <= 102400)
#define CH 8192        // edges per block in scatter pass (391 blocks)
#define CAPB 2688      // bucket capacity (ints for buf/csr, bytes for sbuf)

typedef unsigned short ushort_t;
typedef __attribute__((ext_vector_type(8))) short short8;
typedef __attribute__((ext_vector_type(4))) float f32x4;
typedef __attribute__((ext_vector_type(8))) unsigned short us8v;

static __device__ __forceinline__ float bf2f(ushort_t u) {
    return __uint_as_float(((unsigned)u) << 16);
}
static __device__ __forceinline__ ushort_t f2bf(float f) {
    __hip_bfloat16 h = __float2bfloat16(f);
    return *reinterpret_cast<ushort_t*>(&h);
}
static __device__ __forceinline__ short8 pack8(float4 a, float4 b) {
    short8 r;
    r[0] = (short)f2bf(a.x); r[1] = (short)f2bf(a.y);
    r[2] = (short)f2bf(a.z); r[3] = (short)f2bf(a.w);
    r[4] = (short)f2bf(b.x); r[5] = (short)f2bf(b.y);
    r[6] = (short)f2bf(b.z); r[7] = (short)f2bf(b.w);
    return r;
}

// ---------------- graph build: one-pass capacity-bucket sort ----------------

__global__ void k_initpos(int* __restrict__ gpos, int* __restrict__ spos, int nbuck) {
    int i = blockIdx.x * blockDim.x + threadIdx.x;
    if (i < nbuck) {
        gpos[i] = i * CAPB;
        spos[i] = i * CAPB;
    }
}

// scatter packed (src | dstlow<<17) into dst-bucket capacity regions AND
// (src&63) bytes into src-bucket regions. Block-batched bucket claims.
__global__ __launch_bounds__(256) void p1_scatter(const int* __restrict__ src,
                                                  const int* __restrict__ dst,
                                                  int* __restrict__ gpos,
                                                  int* __restrict__ spos,
                                                  int* __restrict__ buf,
                                                  unsigned char* __restrict__ sbuf,
                                                  int E, int nbuck) {
    __shared__ int hd[MAXBUCK];
    __shared__ int bd[MAXBUCK];
    __shared__ int hs[MAXBUCK];
    __shared__ int bs[MAXBUCK];
    for (int i = threadIdx.x; i < nbuck; i += 256) { hd[i] = 0; hs[i] = 0; }
    __syncthreads();
    int base = blockIdx.x * CH;
    int lim = min(base + CH, E);
    for (int e = base + threadIdx.x; e < lim; e += 256) {
        atomicAdd(&hd[dst[e] >> 6], 1);
        atomicAdd(&hs[src[e] >> 6], 1);
    }
    __syncthreads();
    for (int i = threadIdx.x; i < nbuck; i += 256) {
        int v = hd[i];
        bd[i] = v ? atomicAdd(&gpos[i], v) : 0;
        hd[i] = 0;
        int u = hs[i];
        bs[i] = u ? atomicAdd(&spos[i], u) : 0;
        hs[i] = 0;
    }
    __syncthreads();
    for (int e = base + threadIdx.x; e < lim; e += 256) {
        int d = dst[e], s = src[e];
        int bk = d >> 6;
        int off = atomicAdd(&hd[bk], 1);
        buf[bd[bk] + off] = s | ((d & 63) << 17);
        int sk = s >> 6;
        int off2 = atomicAdd(&hs[sk], 1);
        sbuf[bs[sk] + off2] = (unsigned char)(s & 63);
    }
}

// per-dst-bucket grouping into CSR (+ row_ptr/row_end; csr has inter-bucket gaps)
__global__ __launch_bounds__(256) void p2_group(const int* __restrict__ buf,
                                                const int* __restrict__ gpos,
                                                int* __restrict__ csr,
                                                int* __restrict__ row_ptr,
                                                int* __restrict__ row_end, int N) {
    int bk = blockIdx.x;
    int s0 = bk * CAPB, s1 = gpos[bk];
    __shared__ int cnt[64];
    __shared__ int pos[64];
    int t = threadIdx.x;
    if (t < 64) cnt[t] = 0;
    __syncthreads();
    for (int i = s0 + t; i < s1; i += 256) atomicAdd(&cnt[buf[i] >> 17], 1);
    __syncthreads();
    if (t < 64) {
        int v = cnt[t], s = v;
        #pragma unroll
        for (int off = 1; off < 64; off <<= 1) {
            int u = __shfl_up(s, off);
            if (t >= off) s += u;
        }
        int excl = s - v;
        int node = bk * 64 + t;
        if (node < N) {
            row_ptr[node] = s0 + excl;
            row_end[node] = s0 + excl + v;
        }
        pos[t] = s0 + excl;
    }
    __syncthreads();
    for (int i = s0 + t; i < s1; i += 256) {
        int p = buf[i];
        int off = atomicAdd(&pos[p >> 17], 1);
        csr[off] = p & 0x1FFFF;
    }
}

// per-src-bucket degree count -> dinv
__global__ __launch_bounds__(256) void p2b_deg(const unsigned char* __restrict__ sbuf,
                                               const int* __restrict__ spos,
                                               float* __restrict__ dinv, int N) {
    int bk = blockIdx.x;
    int s0 = bk * CAPB, s1 = spos[bk];
    __shared__ int cnt[64];
    int t = threadIdx.x;
    if (t < 64) cnt[t] = 0;
    __syncthreads();
    for (int i = s0 + t; i < s1; i += 256) atomicAdd(&cnt[sbuf[i]], 1);
    __syncthreads();
    if (t < 64) {
        int node = bk * 64 + t;
        if (node < N) {
            int d = cnt[t];
            dinv[node] = (d > 0) ? rsqrtf((float)d) : 0.0f;
        }
    }
}

// ---------------- Bernstein coefficients ----------------

__global__ void k_coef(const float* __restrict__ temp, float* __restrict__ c,
                       float* __restrict__ temp_out) {
    if (threadIdx.x != 0 || blockIdx.x != 0) return;
    float T[KORD + 1];
    #pragma unroll
    for (int j = 0; j <= KORD; ++j) {
        T[j] = fmaxf(temp[j], 0.0f);
        temp_out[j] = T[j];
    }
    float binom[KORD + 1][KORD + 1];
    for (int n = 0; n <= KORD; ++n) {
        binom[n][0] = 1.0f;
        for (int k = 1; k <= n; ++k)
            binom[n][k] = (k == n) ? 1.0f : binom[n - 1][k - 1] + binom[n - 1][k];
        for (int k = n + 1; k <= KORD; ++k) binom[n][k] = 0.0f;
    }
    for (int m = 0; m <= KORD; ++m) {
        float s = 0.0f;
        for (int j = 0; j <= KORD; ++j) {
            float cj = 0.0f;
            for (int p = 0; p <= j && p <= m; ++p) {
                int q = m - p;
                if (q > KORD - j) continue;
                float t = binom[j][p] * binom[KORD - j][q];
                cj += (p & 1) ? -t : t;
            }
            s += binom[KORD][j] * T[j] * cj;
        }
        c[m] = s * (1.0f / 1024.0f);
    }
}

// ---------------- weight prep: transpose + bf16 ----------------

__global__ void k_prepw(const float* __restrict__ W1, const float* __restrict__ W2,
                        ushort_t* __restrict__ W1t, ushort_t* __restrict__ W2t) {
    int id = blockIdx.x * blockDim.x + threadIdx.x;
    if (id < HIDDEN * NFEAT) {
        int n = id / NFEAT, k = id % NFEAT;
        W1t[id] = f2bf(W1[(size_t)k * HIDDEN + n]);
    } else if (id < HIDDEN * NFEAT + NCLASS * HIDDEN) {
        int j = id - HIDDEN * NFEAT;
        int n = j / HIDDEN, k = j % HIDDEN;
        W2t[j] = f2bf(W2[(size_t)k * NCLASS + n]);
    }
}

// ---------------- GEMM1: h1 = relu(x @ W1 + b1), bf16 MFMA ----------------

__global__ __launch_bounds__(256) void gemm1(const float* __restrict__ x,
                                             const ushort_t* __restrict__ W1t,
                                             const float* __restrict__ b1,
                                             ushort_t* __restrict__ h1, int M) {
    __shared__ char smem[24576];
    char* As = smem;
    char* Bs = smem + 8192;
    const int t = threadIdx.x;
    const int m0 = blockIdx.x * 64;
    const int wid = t >> 6, lane = t & 63;
    const int wr = wid >> 1, wc = wid & 1;
    const int lm = lane & 15, lg = lane >> 4;

    f32x4 acc[2][4];
    #pragma unroll
    for (int i = 0; i < 2; ++i)
        #pragma unroll
        for (int j = 0; j < 4; ++j) acc[i][j] = (f32x4){0.f, 0.f, 0.f, 0.f};

    for (int k0 = 0; k0 < NFEAT; k0 += 64) {
        #pragma unroll
        for (int i = 0; i < 2; ++i) {
            int idx = t + i * 256;
            int r = idx >> 3, c8 = idx & 7;
            float4 v0 = make_float4(0.f, 0.f, 0.f, 0.f), v1 = v0;
            if (m0 + r < M) {
                const float* p = &x[(size_t)(m0 + r) * NFEAT + k0 + c8 * 8];
                v0 = *(const float4*)p;
                v1 = *(const float4*)(p + 4);
            }
            *(short8*)(As + r * 128 + ((c8 * 16) ^ ((r & 7) << 4))) = pack8(v0, v1);
        }
        #pragma unroll
        for (int i = 0; i < 4; ++i) {
            int idx = t + i * 256;
            int r = idx >> 3, c8 = idx & 7;
            short8 v = *(const short8*)&W1t[(size_t)r * NFEAT + k0 + c8 * 8];
            *(short8*)(Bs + r * 128 + ((c8 * 16) ^ ((r & 7) << 4))) = v;
        }
        __syncthreads();
        #pragma unroll
        for (int kk = 0; kk < 64; kk += 32) {
            int kb = (kk + lg * 8) * 2;
            short8 af[2], bfr[4];
            #pragma unroll
            for (int fi = 0; fi < 2; ++fi) {
                int m = wr * 32 + fi * 16 + lm;
                af[fi] = *(const short8*)(As + m * 128 + (kb ^ ((m & 7) << 4)));
            }
            #pragma unroll
            for (int fj = 0; fj < 4; ++fj) {
                int n = wc * 64 + fj * 16 + lm;
                bfr[fj] = *(const short8*)(Bs + n * 128 + (kb ^ ((n & 7) << 4)));
            }
            #pragma unroll
            for (int fi = 0; fi < 2; ++fi)
                #pragma unroll
                for (int fj = 0; fj < 4; ++fj)
                    acc[fi][fj] = __builtin_amdgcn_mfma_f32_16x16x32_bf16(
                        af[fi], bfr[fj], acc[fi][fj], 0, 0, 0);
        }
        __syncthreads();
    }

    ushort_t* Cs = (ushort_t*)smem;
    #pragma unroll
    for (int fi = 0; fi < 2; ++fi)
        #pragma unroll
        for (int fj = 0; fj < 4; ++fj) {
            int col = wc * 64 + fj * 16 + lm;
            float bb = b1[col];
            #pragma unroll
            for (int q = 0; q < 4; ++q) {
                int r = wr * 32 + fi * 16 + lg * 4 + q;
                float z = fmaxf(acc[fi][fj][q] + bb, 0.0f);
                Cs[r * 128 + col] = f2bf(z);
            }
        }
    __syncthreads();
    #pragma unroll
    for (int i = 0; i < 4; ++i) {
        int idx = t + i * 256;
        int r = idx >> 4, c8 = idx & 15;
        if (m0 + r < M)
            *(short8*)&h1[(size_t)(m0 + r) * HIDDEN + c8 * 8] =
                *(const short8*)&Cs[r * 128 + c8 * 8];
    }
}

// ---------------- GEMM2: h = h1 @ W2 + b2 ; emits hb=bf16(h), g0=bf16(dinv*cK*h) ----

__global__ __launch_bounds__(256) void gemm2(const ushort_t* __restrict__ h1,
                                             const ushort_t* __restrict__ W2t,
                                             const float* __restrict__ b2,
                                             const float* __restrict__ dinv,
                                             const float* __restrict__ c,
                                             ushort_t* __restrict__ hb,
                                             ushort_t* __restrict__ g0, int M) {
    __shared__ char smem[49152];
    char* As = smem;
    char* Bs = smem + 32768;
    const int t = threadIdx.x;
    const int m0 = blockIdx.x * 128;
    const int wr = t >> 6, lane = t & 63;
    const int lm = lane & 15, lg = lane >> 4;

    #pragma unroll
    for (int i = 0; i < 8; ++i) {
        int idx = t + i * 256;
        int r = idx >> 4, c8 = idx & 15;
        short8 v = (short8){0, 0, 0, 0, 0, 0, 0, 0};
        if (m0 + r < M) v = *(const short8*)&h1[(size_t)(m0 + r) * HIDDEN + c8 * 8];
        *(short8*)(As + r * 256 + ((c8 * 16) ^ ((r & 7) << 4))) = v;
    }
    #pragma unroll
    for (int i = 0; i < 4; ++i) {
        int idx = t + i * 256;
        int r = idx >> 4, c8 = idx & 15;
        short8 v = *(const short8*)&W2t[(size_t)r * HIDDEN + c8 * 8];
        *(short8*)(Bs + r * 256 + ((c8 * 16) ^ ((r & 7) << 4))) = v;
    }
    __syncthreads();

    f32x4 acc[2][4];
    #pragma unroll
    for (int i = 0; i < 2; ++i)
        #pragma unroll
        for (int j = 0; j < 4; ++j) acc[i][j] = (f32x4){0.f, 0.f, 0.f, 0.f};

    #pragma unroll
    for (int kk = 0; kk < HIDDEN; kk += 32) {
        int kb = (kk + lg * 8) * 2;
        short8 af[2], bfr[4];
        #pragma unroll
        for (int fi = 0; fi < 2; ++fi) {
            int m = wr * 32 + fi * 16 + lm;
            af[fi] = *(const short8*)(As + m * 256 + (kb ^ ((m & 7) << 4)));
        }
        #pragma unroll
        for (int fj = 0; fj < 4; ++fj) {
            int n = fj * 16 + lm;
            bfr[fj] = *(const short8*)(Bs + n * 256 + (kb ^ ((n & 7) << 4)));
        }
        #pragma unroll
        for (int fi = 0; fi < 2; ++fi)
            #pragma unroll
            for (int fj = 0; fj < 4; ++fj)
                acc[fi][fj] = __builtin_amdgcn_mfma_f32_16x16x32_bf16(
                    af[fi], bfr[fj], acc[fi][fj], 0, 0, 0);
    }

    float cK = c[KORD];
    #pragma unroll
    for (int fi = 0; fi < 2; ++fi)
        #pragma unroll
        for (int q = 0; q < 4; ++q) {
            int r = m0 + wr * 32 + fi * 16 + lg * 4 + q;
            if (r < M) {
                float dv = dinv[r];
                #pragma unroll
                for (int fj = 0; fj < 4; ++fj) {
                    int col = fj * 16 + lm;
                    float z = acc[fi][fj][q] + b2[col];
                    size_t o = (size_t)r * NCLASS + col;
                    hb[o] = f2bf(z);
                    g0[o] = f2bf(dv * cK * z);
                }
            }
        }
}

// ---------------- Horner SpMV step: w = A*w_prev + c[cidx]*h ----------------
// octet scheme: 8 edges per wave-load; 8 lanes per edge, ushort8 (8 features, 16B).

__global__ __launch_bounds__(256) void k_adj(const ushort_t* __restrict__ gin,
                                             const ushort_t* __restrict__ hb,
                                             const float* __restrict__ dinv,
                                             const int* __restrict__ row_ptr,
                                             const int* __restrict__ row_end,
                                             const int* __restrict__ csr,
                                             const float* __restrict__ c, int cidx,
                                             ushort_t* __restrict__ gout,
                                             float* __restrict__ out, int last, int N) {
    int wid = blockIdx.x * 4 + (threadIdx.x >> 6);
    int lane = threadIdx.x & 63;
    if (wid >= N) return;
    const int g = lane >> 3;         // edge slot within octet (0..7)
    const int f0 = (lane & 7) * 8;   // feature base
    int b = row_ptr[wid], e = row_end[wid];

    float a[8] = {0.f, 0.f, 0.f, 0.f, 0.f, 0.f, 0.f, 0.f};
    for (int i = b; i < e; i += 32) {
        #pragma unroll
        for (int u = 0; u < 4; ++u) {
            int ei = i + u * 8 + g;
            bool ok = ei < e;
            int s = ok ? csr[ei] : 0;
            us8v v = *(const us8v*)&gin[(size_t)s * NCLASS + f0];
            float m = ok ? 1.0f : 0.0f;
            #pragma unroll
            for (int q = 0; q < 8; ++q) a[q] += m * bf2f(v[q]);
        }
    }
    // combine the 8 edge-groups (lanes with equal lane&7)
    #pragma unroll
    for (int off = 8; off <= 32; off <<= 1)
        #pragma unroll
        for (int q = 0; q < 8; ++q) a[q] += __shfl_xor(a[q], off);

    float dv = dinv[wid];
    float cc = c[cidx];
    size_t o = (size_t)wid * NCLASS + f0;
    us8v hv = *(const us8v*)&hb[o];
    float w[8];
    #pragma unroll
    for (int q = 0; q < 8; ++q) w[q] = dv * a[q] + cc * bf2f(hv[q]);

    if (!last) {
        if (g == 0) {
            us8v r;
            #pragma unroll
            for (int q = 0; q < 8; ++q) r[q] = f2bf(dv * w[q]);
            *(us8v*)&gout[o] = r;
        }
    } else {
        float mx = w[0];
        #pragma unroll
        for (int q = 1; q < 8; ++q) mx = fmaxf(mx, w[q]);
        #pragma unroll
        for (int off = 4; off >= 1; off >>= 1) mx = fmaxf(mx, __shfl_xor(mx, off));
        float s = 0.f;
        #pragma unroll
        for (int q = 0; q < 8; ++q) s += expf(w[q] - mx);
        #pragma unroll
        for (int off = 4; off >= 1; off >>= 1) s += __shfl_xor(s, off);
        float ls = logf(s);
        if (g == 0) {
            float4 r0 = make_float4(w[0] - mx - ls, w[1] - mx - ls,
                                    w[2] - mx - ls, w[3] - mx - ls);
            float4 r1 = make_float4(w[4] - mx - ls, w[5] - mx - ls,
                                    w[6] - mx - ls, w[7] - mx - ls);
            *(float4*)&out[o] = r0;
            *(float4*)&out[o + 4] = r1;
        }
    }
}

// ---------------- launch ----------------

extern "C" void kernel_launch(void* const* d_in, const int* in_sizes, int n_in,
                              void* d_out, int out_size, void* d_ws, size_t ws_size,
                              hipStream_t stream) {
    const float* x = (const float*)d_in[0];
    const int* ei = (const int*)d_in[1];
    const float* W1 = (const float*)d_in[2];
    const float* b1 = (const float*)d_in[3];
    const float* W2 = (const float*)d_in[4];
    const float* b2 = (const float*)d_in[5];
    const float* temp = (const float*)d_in[6];

    const int N = in_sizes[0] / NFEAT;  // 100000
    const int E = in_sizes[1] / 2;      // 3200000
    const int* src = ei;
    const int* dst = ei + E;
    const int nbuck = (N + 63) >> 6;    // 1563

    float* out = (float*)d_out;
    float* temp_out = out + (size_t)N * NCLASS;

    char* ws = (char*)d_ws;
    size_t off = 0;
    auto alloc = [&](size_t bytes) {
        char* p = ws + off;
        off = (off + bytes + 255) & ~(size_t)255;
        return p;
    };
    ushort_t* h1 = (ushort_t*)alloc((size_t)N * HIDDEN * sizeof(ushort_t));  // 25.6MB
    ushort_t* hb = (ushort_t*)alloc((size_t)N * NCLASS * sizeof(ushort_t));
    ushort_t* gA = (ushort_t*)alloc((size_t)N * NCLASS * sizeof(ushort_t));
    ushort_t* gB = (ushort_t*)alloc((size_t)N * NCLASS * sizeof(ushort_t));
    float* dinv = (float*)alloc((size_t)N * sizeof(float));
    int* row_ptr = (int*)alloc((size_t)N * sizeof(int));
    int* row_end = (int*)alloc((size_t)N * sizeof(int));
    int* gpos = (int*)alloc((size_t)MAXBUCK * sizeof(int));
    int* spos = (int*)alloc((size_t)MAXBUCK * sizeof(int));
    int* csr = (int*)alloc((size_t)nbuck * CAPB * sizeof(int));  // 16.8MB
    ushort_t* W1t = (ushort_t*)alloc((size_t)HIDDEN * NFEAT * sizeof(ushort_t));
    ushort_t* W2t = (ushort_t*)alloc((size_t)NCLASS * HIDDEN * sizeof(ushort_t));
    float* c = (float*)alloc(64);
    (void)ws_size;

    // scratch aliased onto h1 (dead until gemm1): buf 16.8MB + sbuf 4.2MB < 25.6MB
    int* buf = (int*)h1;
    unsigned char* sbuf = (unsigned char*)h1 + (size_t)nbuck * CAPB * sizeof(int);

    const int TB = 256;
    const int eg = (E + CH - 1) / CH;  // 391
    const int wgrid = (N + 3) / 4;

    k_initpos<<<(nbuck + TB - 1) / TB, TB, 0, stream>>>(gpos, spos, nbuck);
    p1_scatter<<<eg, TB, 0, stream>>>(src, dst, gpos, spos, buf, sbuf, E, nbuck);
    p2_group<<<nbuck, TB, 0, stream>>>(buf, gpos, csr, row_ptr, row_end, N);
    p2b_deg<<<nbuck, TB, 0, stream>>>(sbuf, spos, dinv, N);

    k_coef<<<1, 64, 0, stream>>>(temp, c, temp_out);
    k_prepw<<<(HIDDEN * NFEAT + NCLASS * HIDDEN + TB - 1) / TB, TB, 0, stream>>>(W1, W2, W1t, W2t);

    gemm1<<<(N + 63) / 64, TB, 0, stream>>>(x, W1t, b1, h1, N);
    gemm2<<<(N + 127) / 128, TB, 0, stream>>>(h1, W2t, b2, dinv, c, hb, gA, N);

    const ushort_t* gin = gA;
    ushort_t* gout = gB;
    for (int s = 1; s <= KORD; ++s) {
        int last = (s == KORD) ? 1 : 0;
        k_adj<<<wgrid, TB, 0, stream>>>(gin, hb, dinv, row_ptr, row_end, csr, c,
                                        KORD - s, gout, out, last, N);
        const ushort_t* tmp = gin;
        gin = gout;
        gout = (ushort_t*)tmp;
    }
}

// Round 15
// 815.264 us; speedup vs baseline: 2.3804x; 1.0188x over previous
//
#include <hip/hip_runtime.h>
#include <hip/hip_bf16.h>
#include <math.h>

// BernNet: h = relu(x@W1+b1)@W2+b2 ; out = sum_m c_m A^m h (Horner) ; log_softmax
// A = D^-1/2 Adj D^-1/2. CSR(dst) via TWO-LEVEL fixed-capacity bucket sort:
// pass1 -> 13 super-buckets (dst>>13, runs ~2.5KB, no write amplification),
// pass2 -> 64-node fine buckets (runs ~256B). deg via parallel src stream.
// Horner SpMV: octet gather (8 lanes/edge, 16B), one node per wave (r7 form).
// HISTORY: nontemporal csr loads REGRESSED +195us (r6). Quarter-plane feature
// split REGRESSED 3x (r9). MFMA row-sum via LDS+tr_read REGRESSED +82us (r10).
// Two-node-per-wave interleave REGRESSED +28us (r11). One-level 391-block
// scatter: 194MB WRITE for 16MB payload (r12 PMC) -> this two-level scheme.

#define NFEAT 512
#define HIDDEN 128
#define NCLASS 64
#define KORD 10
#define CH 8192        // edges per block in pass1 (391 blocks)
#define CAPB 2688      // fine bucket capacity (ints / bytes)
#define SBSH 13        // super-bucket shift (8192 nodes per super)
#define SBSIZE 8192
#define NSBMAX 16
#define SCAP 280000    // super capacity (ints); mean 262K, +36 sigma
#define TCAP 280000    // super capacity for src ushorts
#define FPS 128        // fine buckets per super
#define B2 32          // blocks per super in pass2

typedef unsigned short ushort_t;
typedef __attribute__((ext_vector_type(8))) short short8;
typedef __attribute__((ext_vector_type(4))) float f32x4;
typedef __attribute__((ext_vector_type(8))) unsigned short us8v;

static __device__ __forceinline__ float bf2f(ushort_t u) {
    return __uint_as_float(((unsigned)u) << 16);
}
static __device__ __forceinline__ ushort_t f2bf(float f) {
    __hip_bfloat16 h = __float2bfloat16(f);
    return *reinterpret_cast<ushort_t*>(&h);
}
static __device__ __forceinline__ short8 pack8(float4 a, float4 b) {
    short8 r;
    r[0] = (short)f2bf(a.x); r[1] = (short)f2bf(a.y);
    r[2] = (short)f2bf(a.z); r[3] = (short)f2bf(a.w);
    r[4] = (short)f2bf(b.x); r[5] = (short)f2bf(b.y);
    r[6] = (short)f2bf(b.z); r[7] = (short)f2bf(b.w);
    return r;
}

// ---------------- graph build: two-level capacity-bucket sort ----------------

__global__ void k_initpos(int* __restrict__ gpos, int* __restrict__ spos,
                          int* __restrict__ spos1, int* __restrict__ tpos1,
                          int nbuck, int nsb) {
    int i = blockIdx.x * blockDim.x + threadIdx.x;
    if (i < nbuck) {
        gpos[i] = i * CAPB;
        spos[i] = i * CAPB;
    }
    if (i < nsb) {
        spos1[i] = i * SCAP;
        tpos1[i] = i * TCAP;
    }
}

// pass1: edges -> super-buckets. rec = src | (dst&8191)<<17 ; tsup = src&8191.
__global__ __launch_bounds__(256) void q1_super(const int* __restrict__ src,
                                                const int* __restrict__ dst,
                                                int* __restrict__ spos1,
                                                int* __restrict__ tpos1,
                                                int* __restrict__ sup,
                                                ushort_t* __restrict__ tsup,
                                                int E, int nsb) {
    __shared__ int hd[NSBMAX], bd[NSBMAX], hs[NSBMAX], bs[NSBMAX];
    int t = threadIdx.x;
    if (t < nsb) { hd[t] = 0; hs[t] = 0; }
    __syncthreads();
    int base = blockIdx.x * CH;
    int lim = min(base + CH, E);
    for (int e = base + t; e < lim; e += 256) {
        atomicAdd(&hd[dst[e] >> SBSH], 1);
        atomicAdd(&hs[src[e] >> SBSH], 1);
    }
    __syncthreads();
    if (t < nsb) {
        int v = hd[t];
        bd[t] = v ? atomicAdd(&spos1[t], v) : 0;
        hd[t] = 0;
        int u = hs[t];
        bs[t] = u ? atomicAdd(&tpos1[t], u) : 0;
        hs[t] = 0;
    }
    __syncthreads();
    for (int e = base + t; e < lim; e += 256) {
        int d = dst[e], s = src[e];
        int sb = d >> SBSH;
        int off = atomicAdd(&hd[sb], 1);
        sup[bd[sb] + off] = s | ((d & (SBSIZE - 1)) << 17);
        int tb = s >> SBSH;
        int off2 = atomicAdd(&hs[tb], 1);
        tsup[bs[tb] + off2] = (ushort_t)(s & (SBSIZE - 1));
    }
}

// pass2a: super recs -> fine dst buckets (gpos capacity regions).
__global__ __launch_bounds__(256) void q2_fine(const int* __restrict__ sup,
                                               const int* __restrict__ spos1,
                                               int* __restrict__ gpos,
                                               int* __restrict__ buf) {
    int s = blockIdx.x / B2, blk = blockIdx.x - s * B2;
    int r0 = s * SCAP, r1 = spos1[s];
    int cnt = r1 - r0;
    int share = (cnt + B2 - 1) / B2;
    int a0 = r0 + blk * share;
    int a1 = min(a0 + share, r1);
    __shared__ int hd[FPS], bd[FPS];
    int t = threadIdx.x;
    if (t < FPS) hd[t] = 0;
    __syncthreads();
    for (int i = a0 + t; i < a1; i += 256) atomicAdd(&hd[sup[i] >> 23], 1);
    __syncthreads();
    if (t < FPS) {
        int v = hd[t];
        bd[t] = v ? atomicAdd(&gpos[s * FPS + t], v) : 0;
        hd[t] = 0;
    }
    __syncthreads();
    for (int i = a0 + t; i < a1; i += 256) {
        int r = sup[i];
        int d13 = r >> 17;
        int fl = d13 >> 6;
        int off = atomicAdd(&hd[fl], 1);
        buf[bd[fl] + off] = (r & 0x1FFFF) | ((d13 & 63) << 17);
    }
}

// pass2b: super src ushorts -> fine src byte buckets (spos capacity regions).
__global__ __launch_bounds__(256) void q2b_fine(const ushort_t* __restrict__ tsup,
                                                const int* __restrict__ tpos1,
                                                int* __restrict__ spos,
                                                unsigned char* __restrict__ sbuf) {
    int s = blockIdx.x / B2, blk = blockIdx.x - s * B2;
    int r0 = s * TCAP, r1 = tpos1[s];
    int cnt = r1 - r0;
    int share = (cnt + B2 - 1) / B2;
    int a0 = r0 + blk * share;
    int a1 = min(a0 + share, r1);
    __shared__ int hd[FPS], bd[FPS];
    int t = threadIdx.x;
    if (t < FPS) hd[t] = 0;
    __syncthreads();
    for (int i = a0 + t; i < a1; i += 256) atomicAdd(&hd[tsup[i] >> 6], 1);
    __syncthreads();
    if (t < FPS) {
        int v = hd[t];
        bd[t] = v ? atomicAdd(&spos[s * FPS + t], v) : 0;
        hd[t] = 0;
    }
    __syncthreads();
    for (int i = a0 + t; i < a1; i += 256) {
        int u = tsup[i];
        int fl = u >> 6;
        int off = atomicAdd(&hd[fl], 1);
        sbuf[bd[fl] + off] = (unsigned char)(u & 63);
    }
}

// per-dst-bucket grouping into CSR (+ row_ptr/row_end; csr has inter-bucket gaps)
__global__ __launch_bounds__(256) void p2_group(const int* __restrict__ buf,
                                                const int* __restrict__ gpos,
                                                int* __restrict__ csr,
                                                int* __restrict__ row_ptr,
                                                int* __restrict__ row_end, int N) {
    int bk = blockIdx.x;
    int s0 = bk * CAPB, s1 = gpos[bk];
    __shared__ int cnt[64];
    __shared__ int pos[64];
    int t = threadIdx.x;
    if (t < 64) cnt[t] = 0;
    __syncthreads();
    for (int i = s0 + t; i < s1; i += 256) atomicAdd(&cnt[buf[i] >> 17], 1);
    __syncthreads();
    if (t < 64) {
        int v = cnt[t], s = v;
        #pragma unroll
        for (int off = 1; off < 64; off <<= 1) {
            int u = __shfl_up(s, off);
            if (t >= off) s += u;
        }
        int excl = s - v;
        int node = bk * 64 + t;
        if (node < N) {
            row_ptr[node] = s0 + excl;
            row_end[node] = s0 + excl + v;
        }
        pos[t] = s0 + excl;
    }
    __syncthreads();
    for (int i = s0 + t; i < s1; i += 256) {
        int p = buf[i];
        int off = atomicAdd(&pos[p >> 17], 1);
        csr[off] = p & 0x1FFFF;
    }
}

// per-src-bucket degree count -> dinv
__global__ __launch_bounds__(256) void p2b_deg(const unsigned char* __restrict__ sbuf,
                                               const int* __restrict__ spos,
                                               float* __restrict__ dinv, int N) {
    int bk = blockIdx.x;
    int s0 = bk * CAPB, s1 = spos[bk];
    __shared__ int cnt[64];
    int t = threadIdx.x;
    if (t < 64) cnt[t] = 0;
    __syncthreads();
    for (int i = s0 + t; i < s1; i += 256) atomicAdd(&cnt[sbuf[i]], 1);
    __syncthreads();
    if (t < 64) {
        int node = bk * 64 + t;
        if (node < N) {
            int d = cnt[t];
            dinv[node] = (d > 0) ? rsqrtf((float)d) : 0.0f;
        }
    }
}

// ---------------- Bernstein coefficients ----------------

__global__ void k_coef(const float* __restrict__ temp, float* __restrict__ c,
                       float* __restrict__ temp_out) {
    if (threadIdx.x != 0 || blockIdx.x != 0) return;
    float T[KORD + 1];
    #pragma unroll
    for (int j = 0; j <= KORD; ++j) {
        T[j] = fmaxf(temp[j], 0.0f);
        temp_out[j] = T[j];
    }
    float binom[KORD + 1][KORD + 1];
    for (int n = 0; n <= KORD; ++n) {
        binom[n][0] = 1.0f;
        for (int k = 1; k <= n; ++k)
            binom[n][k] = (k == n) ? 1.0f : binom[n - 1][k - 1] + binom[n - 1][k];
        for (int k = n + 1; k <= KORD; ++k) binom[n][k] = 0.0f;
    }
    for (int m = 0; m <= KORD; ++m) {
        float s = 0.0f;
        for (int j = 0; j <= KORD; ++j) {
            float cj = 0.0f;
            for (int p = 0; p <= j && p <= m; ++p) {
                int q = m - p;
                if (q > KORD - j) continue;
                float t = binom[j][p] * binom[KORD - j][q];
                cj += (p & 1) ? -t : t;
            }
            s += binom[KORD][j] * T[j] * cj;
        }
        c[m] = s * (1.0f / 1024.0f);
    }
}

// ---------------- weight prep: transpose + bf16 ----------------

__global__ void k_prepw(const float* __restrict__ W1, const float* __restrict__ W2,
                        ushort_t* __restrict__ W1t, ushort_t* __restrict__ W2t) {
    int id = blockIdx.x * blockDim.x + threadIdx.x;
    if (id < HIDDEN * NFEAT) {
        int n = id / NFEAT, k = id % NFEAT;
        W1t[id] = f2bf(W1[(size_t)k * HIDDEN + n]);
    } else if (id < HIDDEN * NFEAT + NCLASS * HIDDEN) {
        int j = id - HIDDEN * NFEAT;
        int n = j / HIDDEN, k = j % HIDDEN;
        W2t[j] = f2bf(W2[(size_t)k * NCLASS + n]);
    }
}

// ---------------- GEMM1: h1 = relu(x @ W1 + b1), bf16 MFMA ----------------

__global__ __launch_bounds__(256) void gemm1(const float* __restrict__ x,
                                             const ushort_t* __restrict__ W1t,
                                             const float* __restrict__ b1,
                                             ushort_t* __restrict__ h1, int M) {
    __shared__ char smem[24576];
    char* As = smem;
    char* Bs = smem + 8192;
    const int t = threadIdx.x;
    const int m0 = blockIdx.x * 64;
    const int wid = t >> 6, lane = t & 63;
    const int wr = wid >> 1, wc = wid & 1;
    const int lm = lane & 15, lg = lane >> 4;

    f32x4 acc[2][4];
    #pragma unroll
    for (int i = 0; i < 2; ++i)
        #pragma unroll
        for (int j = 0; j < 4; ++j) acc[i][j] = (f32x4){0.f, 0.f, 0.f, 0.f};

    for (int k0 = 0; k0 < NFEAT; k0 += 64) {
        #pragma unroll
        for (int i = 0; i < 2; ++i) {
            int idx = t + i * 256;
            int r = idx >> 3, c8 = idx & 7;
            float4 v0 = make_float4(0.f, 0.f, 0.f, 0.f), v1 = v0;
            if (m0 + r < M) {
                const float* p = &x[(size_t)(m0 + r) * NFEAT + k0 + c8 * 8];
                v0 = *(const float4*)p;
                v1 = *(const float4*)(p + 4);
            }
            *(short8*)(As + r * 128 + ((c8 * 16) ^ ((r & 7) << 4))) = pack8(v0, v1);
        }
        #pragma unroll
        for (int i = 0; i < 4; ++i) {
            int idx = t + i * 256;
            int r = idx >> 3, c8 = idx & 7;
            short8 v = *(const short8*)&W1t[(size_t)r * NFEAT + k0 + c8 * 8];
            *(short8*)(Bs + r * 128 + ((c8 * 16) ^ ((r & 7) << 4))) = v;
        }
        __syncthreads();
        #pragma unroll
        for (int kk = 0; kk < 64; kk += 32) {
            int kb = (kk + lg * 8) * 2;
            short8 af[2], bfr[4];
            #pragma unroll
            for (int fi = 0; fi < 2; ++fi) {
                int m = wr * 32 + fi * 16 + lm;
                af[fi] = *(const short8*)(As + m * 128 + (kb ^ ((m & 7) << 4)));
            }
            #pragma unroll
            for (int fj = 0; fj < 4; ++fj) {
                int n = wc * 64 + fj * 16 + lm;
                bfr[fj] = *(const short8*)(Bs + n * 128 + (kb ^ ((n & 7) << 4)));
            }
            #pragma unroll
            for (int fi = 0; fi < 2; ++fi)
                #pragma unroll
                for (int fj = 0; fj < 4; ++fj)
                    acc[fi][fj] = __builtin_amdgcn_mfma_f32_16x16x32_bf16(
                        af[fi], bfr[fj], acc[fi][fj], 0, 0, 0);
        }
        __syncthreads();
    }

    ushort_t* Cs = (ushort_t*)smem;
    #pragma unroll
    for (int fi = 0; fi < 2; ++fi)
        #pragma unroll
        for (int fj = 0; fj < 4; ++fj) {
            int col = wc * 64 + fj * 16 + lm;
            float bb = b1[col];
            #pragma unroll
            for (int q = 0; q < 4; ++q) {
                int r = wr * 32 + fi * 16 + lg * 4 + q;
                float z = fmaxf(acc[fi][fj][q] + bb, 0.0f);
                Cs[r * 128 + col] = f2bf(z);
            }
        }
    __syncthreads();
    #pragma unroll
    for (int i = 0; i < 4; ++i) {
        int idx = t + i * 256;
        int r = idx >> 4, c8 = idx & 15;
        if (m0 + r < M)
            *(short8*)&h1[(size_t)(m0 + r) * HIDDEN + c8 * 8] =
                *(const short8*)&Cs[r * 128 + c8 * 8];
    }
}

// ---------------- GEMM2: h = h1 @ W2 + b2 ; emits hb=bf16(h), g0=bf16(dinv*cK*h) ----

__global__ __launch_bounds__(256) void gemm2(const ushort_t* __restrict__ h1,
                                             const ushort_t* __restrict__ W2t,
                                             const float* __restrict__ b2,
                                             const float* __restrict__ dinv,
                                             const float* __restrict__ c,
                                             ushort_t* __restrict__ hb,
                                             ushort_t* __restrict__ g0, int M) {
    __shared__ char smem[49152];
    char* As = smem;
    char* Bs = smem + 32768;
    const int t = threadIdx.x;
    const int m0 = blockIdx.x * 128;
    const int wr = t >> 6, lane = t & 63;
    const int lm = lane & 15, lg = lane >> 4;

    #pragma unroll
    for (int i = 0; i < 8; ++i) {
        int idx = t + i * 256;
        int r = idx >> 4, c8 = idx & 15;
        short8 v = (short8){0, 0, 0, 0, 0, 0, 0, 0};
        if (m0 + r < M) v = *(const short8*)&h1[(size_t)(m0 + r) * HIDDEN + c8 * 8];
        *(short8*)(As + r * 256 + ((c8 * 16) ^ ((r & 7) << 4))) = v;
    }
    #pragma unroll
    for (int i = 0; i < 4; ++i) {
        int idx = t + i * 256;
        int r = idx >> 4, c8 = idx & 15;
        short8 v = *(const short8*)&W2t[(size_t)r * HIDDEN + c8 * 8];
        *(short8*)(Bs + r * 256 + ((c8 * 16) ^ ((r & 7) << 4))) = v;
    }
    __syncthreads();

    f32x4 acc[2][4];
    #pragma unroll
    for (int i = 0; i < 2; ++i)
        #pragma unroll
        for (int j = 0; j < 4; ++j) acc[i][j] = (f32x4){0.f, 0.f, 0.f, 0.f};

    #pragma unroll
    for (int kk = 0; kk < HIDDEN; kk += 32) {
        int kb = (kk + lg * 8) * 2;
        short8 af[2], bfr[4];
        #pragma unroll
        for (int fi = 0; fi < 2; ++fi) {
            int m = wr * 32 + fi * 16 + lm;
            af[fi] = *(const short8*)(As + m * 256 + (kb ^ ((m & 7) << 4)));
        }
        #pragma unroll
        for (int fj = 0; fj < 4; ++fj) {
            int n = fj * 16 + lm;
            bfr[fj] = *(const short8*)(Bs + n * 256 + (kb ^ ((n & 7) << 4)));
        }
        #pragma unroll
        for (int fi = 0; fi < 2; ++fi)
            #pragma unroll
            for (int fj = 0; fj < 4; ++fj)
                acc[fi][fj] = __builtin_amdgcn_mfma_f32_16x16x32_bf16(
                    af[fi], bfr[fj], acc[fi][fj], 0, 0, 0);
    }

    float cK = c[KORD];
    #pragma unroll
    for (int fi = 0; fi < 2; ++fi)
        #pragma unroll
        for (int q = 0; q < 4; ++q) {
            int r = m0 + wr * 32 + fi * 16 + lg * 4 + q;
            if (r < M) {
                float dv = dinv[r];
                #pragma unroll
                for (int fj = 0; fj < 4; ++fj) {
                    int col = fj * 16 + lm;
                    float z = acc[fi][fj][q] + b2[col];
                    size_t o = (size_t)r * NCLASS + col;
                    hb[o] = f2bf(z);
                    g0[o] = f2bf(dv * cK * z);
                }
            }
        }
}

// ---------------- Horner SpMV step: w = A*w_prev + c[cidx]*h ----------------
// octet scheme: 8 edges per wave-load; 8 lanes per edge, ushort8 (8 features, 16B).

__global__ __launch_bounds__(256) void k_adj(const ushort_t* __restrict__ gin,
                                             const ushort_t* __restrict__ hb,
                                             const float* __restrict__ dinv,
                                             const int* __restrict__ row_ptr,
                                             const int* __restrict__ row_end,
                                             const int* __restrict__ csr,
                                             const float* __restrict__ c, int cidx,
                                             ushort_t* __restrict__ gout,
                                             float* __restrict__ out, int last, int N) {
    int wid = blockIdx.x * 4 + (threadIdx.x >> 6);
    int lane = threadIdx.x & 63;
    if (wid >= N) return;
    const int g = lane >> 3;         // edge slot within octet (0..7)
    const int f0 = (lane & 7) * 8;   // feature base
    int b = row_ptr[wid], e = row_end[wid];

    float a[8] = {0.f, 0.f, 0.f, 0.f, 0.f, 0.f, 0.f, 0.f};
    for (int i = b; i < e; i += 32) {
        #pragma unroll
        for (int u = 0; u < 4; ++u) {
            int ei = i + u * 8 + g;
            bool ok = ei < e;
            int s = ok ? csr[ei] : 0;
            us8v v = *(const us8v*)&gin[(size_t)s * NCLASS + f0];
            float m = ok ? 1.0f : 0.0f;
            #pragma unroll
            for (int q = 0; q < 8; ++q) a[q] += m * bf2f(v[q]);
        }
    }
    // combine the 8 edge-groups (lanes with equal lane&7)
    #pragma unroll
    for (int off = 8; off <= 32; off <<= 1)
        #pragma unroll
        for (int q = 0; q < 8; ++q) a[q] += __shfl_xor(a[q], off);

    float dv = dinv[wid];
    float cc = c[cidx];
    size_t o = (size_t)wid * NCLASS + f0;
    us8v hv = *(const us8v*)&hb[o];
    float w[8];
    #pragma unroll
    for (int q = 0; q < 8; ++q) w[q] = dv * a[q] + cc * bf2f(hv[q]);

    if (!last) {
        if (g == 0) {
            us8v r;
            #pragma unroll
            for (int q = 0; q < 8; ++q) r[q] = f2bf(dv * w[q]);
            *(us8v*)&gout[o] = r;
        }
    } else {
        float mx = w[0];
        #pragma unroll
        for (int q = 1; q < 8; ++q) mx = fmaxf(mx, w[q]);
        #pragma unroll
        for (int off = 4; off >= 1; off >>= 1) mx = fmaxf(mx, __shfl_xor(mx, off));
        float s = 0.f;
        #pragma unroll
        for (int q = 0; q < 8; ++q) s += expf(w[q] - mx);
        #pragma unroll
        for (int off = 4; off >= 1; off >>= 1) s += __shfl_xor(s, off);
        float ls = logf(s);
        if (g == 0) {
            float4 r0 = make_float4(w[0] - mx - ls, w[1] - mx - ls,
                                    w[2] - mx - ls, w[3] - mx - ls);
            float4 r1 = make_float4(w[4] - mx - ls, w[5] - mx - ls,
                                    w[6] - mx - ls, w[7] - mx - ls);
            *(float4*)&out[o] = r0;
            *(float4*)&out[o + 4] = r1;
        }
    }
}

// ---------------- launch ----------------

extern "C" void kernel_launch(void* const* d_in, const int* in_sizes, int n_in,
                              void* d_out, int out_size, void* d_ws, size_t ws_size,
                              hipStream_t stream) {
    const float* x = (const float*)d_in[0];
    const int* ei = (const int*)d_in[1];
    const float* W1 = (const float*)d_in[2];
    const float* b1 = (const float*)d_in[3];
    const float* W2 = (const float*)d_in[4];
    const float* b2 = (const float*)d_in[5];
    const float* temp = (const float*)d_in[6];

    const int N = in_sizes[0] / NFEAT;  // 100000
    const int E = in_sizes[1] / 2;      // 3200000
    const int* src = ei;
    const int* dst = ei + E;
    const int nbuck = (N + 63) >> 6;            // 1563
    const int nsb = (N + SBSIZE - 1) >> SBSH;   // 13

    float* out = (float*)d_out;
    float* temp_out = out + (size_t)N * NCLASS;

    char* ws = (char*)d_ws;
    size_t off = 0;
    auto alloc = [&](size_t bytes) {
        char* p = ws + off;
        off = (off + bytes + 255) & ~(size_t)255;
        return p;
    };
    ushort_t* h1 = (ushort_t*)alloc((size_t)N * HIDDEN * sizeof(ushort_t));  // 25.6MB
    ushort_t* hb = (ushort_t*)alloc((size_t)N * NCLASS * sizeof(ushort_t));
    ushort_t* gA = (ushort_t*)alloc((size_t)N * NCLASS * sizeof(ushort_t));  // 12.8MB
    ushort_t* gB = (ushort_t*)alloc((size_t)N * NCLASS * sizeof(ushort_t));  // 12.8MB
    float* dinv = (float*)alloc((size_t)N * sizeof(float));
    int* row_ptr = (int*)alloc((size_t)N * sizeof(int));
    int* row_end = (int*)alloc((size_t)N * sizeof(int));
    int* gpos = (int*)alloc((size_t)nbuck * sizeof(int));
    int* spos = (int*)alloc((size_t)nbuck * sizeof(int));
    int* spos1 = (int*)alloc((size_t)NSBMAX * sizeof(int));
    int* tpos1 = (int*)alloc((size_t)NSBMAX * sizeof(int));
    int* csr = (int*)alloc((size_t)nbuck * CAPB * sizeof(int));  // 16.8MB
    ushort_t* W1t = (ushort_t*)alloc((size_t)HIDDEN * NFEAT * sizeof(ushort_t));
    ushort_t* W2t = (ushort_t*)alloc((size_t)NCLASS * HIDDEN * sizeof(ushort_t));
    float* c = (float*)alloc(64);
    (void)ws_size;

    // super scratch aliased onto h1 (dead until gemm1): 14.56 + 7.28 = 21.8 < 25.6MB
    int* sup = (int*)h1;
    ushort_t* tsup = (ushort_t*)((char*)h1 + (size_t)nsb * SCAP * sizeof(int));
    // fine scratch aliased onto gA..gB (dead until gemm2): 16.8 + 4.2 = 21 < 25.6MB
    int* buf = (int*)gA;
    unsigned char* sbuf = (unsigned char*)gA + (size_t)nbuck * CAPB * sizeof(int);

    const int TB = 256;
    const int eg = (E + CH - 1) / CH;  // 391
    const int wgrid = (N + 3) / 4;

    k_initpos<<<(nbuck + TB - 1) / TB, TB, 0, stream>>>(gpos, spos, spos1, tpos1,
                                                        nbuck, nsb);
    q1_super<<<eg, TB, 0, stream>>>(src, dst, spos1, tpos1, sup, tsup, E, nsb);
    q2_fine<<<nsb * B2, TB, 0, stream>>>(sup, spos1, gpos, buf);
    q2b_fine<<<nsb * B2, TB, 0, stream>>>(tsup, tpos1, spos, sbuf);
    p2_group<<<nbuck, TB, 0, stream>>>(buf, gpos, csr, row_ptr, row_end, N);
    p2b_deg<<<nbuck, TB, 0, stream>>>(sbuf, spos, dinv, N);

    k_coef<<<1, 64, 0, stream>>>(temp, c, temp_out);
    k_prepw<<<(HIDDEN * NFEAT + NCLASS * HIDDEN + TB - 1) / TB, TB, 0, stream>>>(W1, W2, W1t, W2t);

    gemm1<<<(N + 63) / 64, TB, 0, stream>>>(x, W1t, b1, h1, N);
    gemm2<<<(N + 127) / 128, TB, 0, stream>>>(h1, W2t, b2, dinv, c, hb, gA, N);

    const ushort_t* gin = gA;
    ushort_t* gout = gB;
    for (int s = 1; s <= KORD; ++s) {
        int last = (s == KORD) ? 1 : 0;
        k_adj<<<wgrid, TB, 0, stream>>>(gin, hb, dinv, row_ptr, row_end, csr, c,
                                        KORD - s, gout, out, last, N);
        const ushort_t* tmp = gin;
        gin = gout;
        gout = (ushort_t*)tmp;
    }
}